// Round 1
// 683.385 us; speedup vs baseline: 1.0026x; 1.0026x over previous
//
#include <hip/hip_runtime.h>

// ---------------------------------------------------------------------------
// SLAYER-style spiking CNN forward pass, MI355X.  Round 3.
//
// psp (SRM alpha kernel) as double-exponential IIR cascade (exact):
//   eps[k] = (e/tau)*k*a^k, a = exp(-1/tau)
//   g1[t] = x[t] + a*g1[t-1]; g2[t] = g1[t] + a*g2[t-1]; u = (e/tau)*(g2-g1)
//
// R3 (this round): k_conv2 inner sum split into 10 independent f64
// accumulator chains (was one 80-deep serial chain -> latency-bound at
// VALUBusy 61%).  Both conv kernels: double-buffered row masks with the
// next-t global load issued before conv compute (latency hidden), barriers
// cut 3->2 (conv2) and 4->2 (conv1, via double-buffered spkP + deferred
// m2 assembly).  IIR order and LUT contents unchanged; only the conv
// partial-sum association changed (f64-safe vs ~1e-7 threshold margins).
// ---------------------------------------------------------------------------

namespace {
constexpr int B = 32, T = 100;
constexpr double A1 = 0.90483741803595957;  // exp(-1/10)
constexpr double CE = 0.27182818284590452;  // e/10

// workspace byte offsets
constexpr size_t OFF_M1 = 0;                                  // u32 [B*T][28]
constexpr size_t OFF_M2 = OFF_M1 + (size_t)B * T * 28 * 4;    // u32 [B*T][16][14]
constexpr size_t OFF_S4 = OFF_M2 + (size_t)B * T * 224 * 4;   // u8  [B*T][1568]
constexpr size_t OFF_D5 = OFF_S4 + (size_t)B * T * 1568;      // f64 [B*T][410]
constexpr size_t OFF_S5 = OFF_D5 + (size_t)B * T * 410 * 8;   // u8  [B*T][410]
constexpr size_t OFF_D6 = OFF_S5 + (size_t)B * T * 410;       // f64 [B*T][10]
constexpr size_t OFF_WT = OFF_D6 + (size_t)B * T * 10 * 8;    // f32 [1568][410]
}  // namespace

// Stage 0: rate encode + bit-pack rows.  Thread per (b,y,t); loops x.
__global__ void k_encode_pack(const float* __restrict__ img, const float* __restrict__ ru,
                              unsigned int* __restrict__ m1) {
  int i = blockIdx.x * 256 + threadIdx.x;
  if (i >= B * 28 * T) return;
  int t = i % T;
  int y = (i / T) % 28;
  int b = i / (T * 28);
  unsigned int m = 0;
  const float* rb = ru + ((size_t)b * 784 + y * 28) * T + t;
  const float* ib = img + b * 784 + y * 28;
  for (int x = 0; x < 28; x++) {
    m |= (rb[(size_t)x * T] < ib[x]) ? (1u << x) : 0u;
  }
  m1[((size_t)b * T + t) * 28 + y] = m;
}

// Stage 1 fused: conv1 (1->16,5x5,pad2) + psp + spike + pool2 + psp + spike.
// Block = (b,o).  Double-buffered mrow + prefetch; double-buffered spkP with
// m2 assembly deferred one iteration -> 2 barriers/t.
__global__ __launch_bounds__(256) void k_conv1(const unsigned int* __restrict__ m1,
                                               const float* __restrict__ w1,
                                               unsigned int* __restrict__ m2) {
  __shared__ double lut[160];            // [dy][32]
  __shared__ unsigned int mrow[2][32];   // rows iy=-2..29 at idx iy+2; guards 0
  __shared__ unsigned char spk[784];
  __shared__ unsigned char spkP[2][196];
  int o = blockIdx.x % 16, b = blockIdx.x / 16;
  int tid = threadIdx.x;
  if (tid < 160) {
    int dy = tid / 32, f = tid % 32;
    double v = 0.0;
    const float* wb = w1 + o * 25 + dy * 5;
#pragma unroll
    for (int dx = 0; dx < 5; dx++)
      if ((f >> dx) & 1) v += (double)wb[dx];
    lut[tid] = v;
  }
  if (tid < 32) {
    mrow[0][tid] = 0;  // guards (0,1,30,31) stay 0 forever
    mrow[1][tid] = 0;
  }
  int y = tid / 7, xg = tid % 7;     // conv coords: 28 rows x 7 groups of 4 px
  int py = tid / 14, px = tid % 14;  // pooled coords
  bool act = tid < 196;
  double g1[4] = {0, 0, 0, 0}, g2[4] = {0, 0, 0, 0};
  double p1 = 0.0, p2 = 0.0;
  const unsigned int* m1b = m1 + (size_t)b * T * 28;
  if (tid < 28) mrow[0][tid + 2] = m1b[tid] << 2;  // stage t=0 (pre-shifted)
  __syncthreads();
  for (int t = 0; t < T; t++) {
    int cur = t & 1, nxt = cur ^ 1;
    // issue next-t global load early; hidden under conv compute
    bool dold = (tid < 28) && (t + 1 < T);
    unsigned int ldv = 0;
    if (dold) ldv = m1b[(t + 1) * 28 + tid] << 2;
    if (act) {
      double s0 = 0, s1 = 0, s2 = 0, s3 = 0;
      int xb = xg * 4;
      const unsigned int* mc = mrow[cur];
#pragma unroll
      for (int dy = 0; dy < 5; dy++) {
        unsigned int m = mc[y + dy];
        const double* ld = lut + dy * 32;
        s0 += ld[(m >> (xb + 0)) & 31];
        s1 += ld[(m >> (xb + 1)) & 31];
        s2 += ld[(m >> (xb + 2)) & 31];
        s3 += ld[(m >> (xb + 3)) & 31];
      }
      g1[0] = s0 + A1 * g1[0]; g2[0] = g1[0] + A1 * g2[0];
      g1[1] = s1 + A1 * g1[1]; g2[1] = g1[1] + A1 * g2[1];
      g1[2] = s2 + A1 * g1[2]; g2[2] = g1[2] + A1 * g2[2];
      g1[3] = s3 + A1 * g1[3]; g2[3] = g1[3] + A1 * g2[3];
      unsigned char* sp = spk + y * 28 + xb;
      sp[0] = (CE * (g2[0] - g1[0]) >= 1.0) ? 1 : 0;
      sp[1] = (CE * (g2[1] - g1[1]) >= 1.0) ? 1 : 0;
      sp[2] = (CE * (g2[2] - g1[2]) >= 1.0) ? 1 : 0;
      sp[3] = (CE * (g2[3] - g1[3]) >= 1.0) ? 1 : 0;
    }
    if (dold) mrow[nxt][tid + 2] = ldv;
    __syncthreads();  // spk ready for pool; mrow[nxt] ready for t+1
    if (act) {
      const unsigned char* r0 = spk + (2 * py) * 28 + 2 * px;
      int sum = (int)r0[0] + (int)r0[1] + (int)r0[28] + (int)r0[29];
      double s = 1.1 * (double)sum;
      p1 = s + A1 * p1;
      p2 = p1 + A1 * p2;
      spkP[cur][tid] = (CE * (p2 - p1) >= 1.0) ? 1 : 0;
    }
    if (tid < 14 && t > 0) {  // assemble row for t-1 from the other buffer
      unsigned int m = 0;
      const unsigned char* rp = spkP[nxt] + tid * 14;
#pragma unroll
      for (int xx = 0; xx < 14; xx++) m |= ((unsigned int)rp[xx]) << xx;
      m2[((size_t)(b * T + (t - 1)) * 16 + o) * 14 + tid] = m;
    }
    __syncthreads();  // spkP[cur] complete before t+1 assemble; spk free
  }
  if (tid < 14) {  // epilogue: row T-1
    unsigned int m = 0;
    const unsigned char* rp = spkP[(T - 1) & 1] + tid * 14;
#pragma unroll
    for (int xx = 0; xx < 14; xx++) m |= ((unsigned int)rp[xx]) << xx;
    m2[((size_t)(b * T + (T - 1)) * 16 + o) * 14 + tid] = m;
  }
}

// One dy-row of the conv2 sum: 16 ci lookups split across two accumulators.
#define C2DY(DY, SA, SB)                                  \
  do {                                                    \
    const uint4* q = (const uint4*)(mc + (y + DY) * 16);  \
    uint4 qa = q[0], qb = q[1], qc = q[2], qd = q[3];     \
    const double* lb = lut + DY * 32;                     \
    SA += lb[0 * 160 + ((qa.x >> x) & 31)];               \
    SA += lb[1 * 160 + ((qa.y >> x) & 31)];               \
    SA += lb[2 * 160 + ((qa.z >> x) & 31)];               \
    SA += lb[3 * 160 + ((qa.w >> x) & 31)];               \
    SA += lb[4 * 160 + ((qb.x >> x) & 31)];               \
    SA += lb[5 * 160 + ((qb.y >> x) & 31)];               \
    SA += lb[6 * 160 + ((qb.z >> x) & 31)];               \
    SA += lb[7 * 160 + ((qb.w >> x) & 31)];               \
    SB += lb[8 * 160 + ((qc.x >> x) & 31)];               \
    SB += lb[9 * 160 + ((qc.y >> x) & 31)];               \
    SB += lb[10 * 160 + ((qc.z >> x) & 31)];              \
    SB += lb[11 * 160 + ((qc.w >> x) & 31)];              \
    SB += lb[12 * 160 + ((qd.x >> x) & 31)];              \
    SB += lb[13 * 160 + ((qd.y >> x) & 31)];              \
    SB += lb[14 * 160 + ((qd.z >> x) & 31)];              \
    SB += lb[15 * 160 + ((qd.w >> x) & 31)];              \
  } while (0)

// Stage 3 fused: conv2 (16->32,5x5,pad2) + psp + spike + pool2 + psp + spike.
// Block = (b,o).  10 independent f64 accumulator chains (2 per dy),
// double-buffered mrow2 + early global prefetch -> 2 barriers/t.
__global__ __launch_bounds__(256) void k_conv2(const unsigned int* __restrict__ m2,
                                               const float* __restrict__ w2,
                                               unsigned char* __restrict__ s4) {
  __shared__ double lut[2560];            // [ci][dy][32]  (20480 B)
  __shared__ unsigned int mrow2[2][288];  // [buf][row 0..17][ci]; guard rows 0,1,16,17
  __shared__ unsigned char spk[196];
  int o = blockIdx.x % 32, b = blockIdx.x / 32;
  int tid = threadIdx.x;
  for (int e = tid; e < 2560; e += 256) {
    int ci = e / 160, rr = e % 160, dy = rr / 32, f = rr % 32;
    double v = 0.0;
    const float* wb = w2 + o * 400 + ci * 25 + dy * 5;
#pragma unroll
    for (int dx = 0; dx < 5; dx++)
      if ((f >> dx) & 1) v += (double)wb[dx];
    lut[e] = v;  // e == (ci*5+dy)*32 + f
  }
  for (int k = tid; k < 288; k += 256) {
    mrow2[0][k] = 0;
    mrow2[1][k] = 0;
  }
  int y = tid / 14, x = tid % 14;
  int py = tid / 7, px = tid % 7;
  bool act = tid < 196;
  int lci = tid / 14, lr = tid % 14;  // loader coords (tid<224)
  double g1 = 0.0, g2 = 0.0, p1 = 0.0, p2 = 0.0;
  const unsigned int* m2b = m2 + (size_t)b * T * 224;
  if (tid < 224) mrow2[0][(lr + 2) * 16 + lci] = m2b[tid] << 2;  // stage t=0
  __syncthreads();
  for (int t = 0; t < T; t++) {
    int cur = t & 1, nxt = cur ^ 1;
    // issue next-t global loads early; latency hidden under conv compute
    bool dold = (tid < 224) && (t + 1 < T);
    unsigned int ldv = 0;
    if (dold) ldv = m2b[(size_t)(t + 1) * 224 + tid] << 2;
    if (act) {
      const unsigned int* mc = mrow2[cur];
      double a0 = 0, b0 = 0, a1 = 0, b1 = 0, a2 = 0, b2 = 0, a3 = 0, b3 = 0,
             a4 = 0, b4 = 0;
      C2DY(0, a0, b0);
      C2DY(1, a1, b1);
      C2DY(2, a2, b2);
      C2DY(3, a3, b3);
      C2DY(4, a4, b4);
      double s = (((a0 + b0) + (a1 + b1)) + ((a2 + b2) + (a3 + b3))) + (a4 + b4);
      g1 = s + A1 * g1;
      g2 = g1 + A1 * g2;
      spk[tid] = (CE * (g2 - g1) >= 1.0) ? 1 : 0;
    }
    if (dold) mrow2[nxt][(lr + 2) * 16 + lci] = ldv;
    __syncthreads();  // spk ready for pool; mrow2[nxt] ready for t+1
    if (tid < 49) {
      const unsigned char* r0 = spk + (2 * py) * 14 + 2 * px;
      int sum = (int)r0[0] + (int)r0[1] + (int)r0[14] + (int)r0[15];
      double s = 1.1 * (double)sum;
      p1 = s + A1 * p1;
      p2 = p1 + A1 * p2;
      s4[(size_t)(b * T + t) * 1568 + o * 49 + tid] = (CE * (p2 - p1) >= 1.0) ? 1 : 0;
    }
    __syncthreads();  // pool done reading spk before t+1 overwrites it
  }
}

// Transpose wf1 [410][1568] -> wt [1568][410] for coalesced dense1 reads.
__global__ void k_transpose(const float* __restrict__ wf1, float* __restrict__ wt) {
  int i = blockIdx.x * 256 + threadIdx.x;
  if (i >= 410 * 1568) return;
  int col = i % 410, row = i / 410;
  wt[i] = wf1[col * 1568 + row];
}

// Stage 5a: dense1 matmul.  Block = 64 o-lanes x 4 bt-groups; 16 (b,t) columns in LDS.
__global__ __launch_bounds__(256) void k_dense1(const unsigned char* __restrict__ s4,
                                                const float* __restrict__ wt,
                                                double* __restrict__ d5) {
  __shared__ unsigned char sl[16 * 1568];  // 25088 B
  int obase = blockIdx.x * 64;   // gridDim.x = 7
  int btbase = blockIdx.y * 16;  // gridDim.y = 200
  int tid = threadIdx.x;
  int olane = tid % 64, bts = tid / 64;
  const unsigned int* src = (const unsigned int*)(s4 + (size_t)btbase * 1568);
  unsigned int* dst = (unsigned int*)sl;
  for (int k = tid; k < 6272; k += 256) dst[k] = src[k];
  __syncthreads();
  int o = obase + olane;
  bool store = o < 410;
  int osafe = store ? o : 409;
  double a0 = 0.0, a1 = 0.0, a2 = 0.0, a3 = 0.0;
  const unsigned char* c0 = sl + (bts * 4 + 0) * 1568;
  const unsigned char* c1 = sl + (bts * 4 + 1) * 1568;
  const unsigned char* c2 = sl + (bts * 4 + 2) * 1568;
  const unsigned char* c3 = sl + (bts * 4 + 3) * 1568;
  for (int i = 0; i < 1568; i++) {
    double wv = (double)wt[(size_t)i * 410 + osafe];
    a0 += wv * (double)c0[i];
    a1 += wv * (double)c1[i];
    a2 += wv * (double)c2[i];
    a3 += wv * (double)c3[i];
  }
  if (store) {
    d5[(size_t)(btbase + bts * 4 + 0) * 410 + o] = a0;
    d5[(size_t)(btbase + bts * 4 + 1) * 410 + o] = a1;
    d5[(size_t)(btbase + bts * 4 + 2) * 410 + o] = a2;
    d5[(size_t)(btbase + bts * 4 + 3) * 410 + o] = a3;
  }
}

// Stage 5b: psp + spike over dense1 output.  One thread per (b,o).
__global__ void k_psp5(const double* __restrict__ d5, unsigned char* __restrict__ s5) {
  int tid = blockIdx.x * 256 + threadIdx.x;
  if (tid >= B * 410) return;
  int o = tid % 410, b = tid / 410;
  double g1 = 0.0, g2 = 0.0;
  for (int t = 0; t < T; t++) {
    double s = d5[(size_t)(b * T + t) * 410 + o];
    g1 = s + A1 * g1;
    g2 = g1 + A1 * g2;
    s5[(size_t)(b * T + t) * 410 + o] = (CE * (g2 - g1) >= 1.0) ? 1 : 0;
  }
}

// Stage 6a: dense2 matmul.  One thread per (bt,o).
__global__ void k_dense2(const unsigned char* __restrict__ s5, const float* __restrict__ wf2,
                         double* __restrict__ d6) {
  int tid = blockIdx.x * 256 + threadIdx.x;
  if (tid >= B * T * 10) return;
  int o = tid % 10, bt = tid / 10;
  const unsigned char* sr = s5 + (size_t)bt * 410;
  const float* wr = wf2 + o * 410;
  double s = 0.0;
  for (int i = 0; i < 410; i++) s += (double)wr[i] * (double)sr[i];
  d6[tid] = s;
}

// Stage 6b: final psp + spike -> d_out [b][o][t] f32.
__global__ void k_psp6(const double* __restrict__ d6, float* __restrict__ out) {
  int tid = blockIdx.x * 256 + threadIdx.x;
  if (tid >= B * 10) return;
  int o = tid % 10, b = tid / 10;
  double g1 = 0.0, g2 = 0.0;
  for (int t = 0; t < T; t++) {
    double s = d6[(size_t)(b * T + t) * 10 + o];
    g1 = s + A1 * g1;
    g2 = g1 + A1 * g2;
    out[(size_t)b * 1000 + o * 100 + t] = (CE * (g2 - g1) >= 1.0) ? 1.0f : 0.0f;
  }
}

extern "C" void kernel_launch(void* const* d_in, const int* in_sizes, int n_in,
                              void* d_out, int out_size, void* d_ws, size_t ws_size,
                              hipStream_t stream) {
  const float* img = (const float*)d_in[0];
  const float* ru = (const float*)d_in[1];
  const float* w1 = (const float*)d_in[2];
  const float* w2 = (const float*)d_in[3];
  const float* wf1 = (const float*)d_in[4];
  const float* wf2 = (const float*)d_in[5];

  unsigned char* ws = (unsigned char*)d_ws;
  unsigned int* m1 = (unsigned int*)(ws + OFF_M1);
  unsigned int* m2 = (unsigned int*)(ws + OFF_M2);
  unsigned char* s4 = ws + OFF_S4;
  double* d5 = (double*)(ws + OFF_D5);
  unsigned char* s5 = ws + OFF_S5;
  double* d6 = (double*)(ws + OFF_D6);
  float* wt = (float*)(ws + OFF_WT);
  float* out = (float*)d_out;

  k_encode_pack<<<(B * 28 * T + 255) / 256, 256, 0, stream>>>(img, ru, m1);
  k_transpose<<<(410 * 1568 + 255) / 256, 256, 0, stream>>>(wf1, wt);
  k_conv1<<<B * 16, 256, 0, stream>>>(m1, w1, m2);
  k_conv2<<<B * 32, 256, 0, stream>>>(m2, w2, s4);
  k_dense1<<<dim3(7, 200), 256, 0, stream>>>(s4, wt, d5);
  k_psp5<<<(B * 410 + 255) / 256, 256, 0, stream>>>(d5, s5);
  k_dense2<<<(B * T * 10 + 255) / 256, 256, 0, stream>>>(s5, wf2, d6);
  k_psp6<<<2, 256, 0, stream>>>(d6, out);
}

// Round 2
// 615.879 us; speedup vs baseline: 1.1125x; 1.1096x over previous
//
#include <hip/hip_runtime.h>

// ---------------------------------------------------------------------------
// SLAYER-style spiking CNN forward pass, MI355X.  Round 4.
//
// psp (SRM alpha kernel) as double-exponential IIR cascade (exact):
//   g1[t] = x[t] + a*g1[t-1]; g2[t] = g1[t] + a*g2[t-1]; u = (e/tau)*(g2-g1)
//
// R4: conv2 rewritten as exact integer MFMA (k_limbs + k_conv2m).
//   Weights decomposed into 5 signed base-256 digits of round(w*2^39)
//   (quantization ~1e-12 per weight, exact thereafter: i8 MFMA -> i32 exact,
//   limb recombine in f64 exact).  R1-R3 conv2 was LDS-pipe-bound (measured
//   6940 cyc/CU/t == LDS instr model); MFMA moves the 1.57G LDS LUT gathers
//   onto the matrix pipe.  Block = (b, row-pair): 4 waves, each one limb
//   (+1/4 of limb 4); B-fragments built in-register from bitmasks; fused
//   IIR + spike + 2x2 pool (row-pair == pool window).  Everything else
//   unchanged from R3.
// ---------------------------------------------------------------------------

namespace {
constexpr int B = 32, T = 100;
constexpr double A1 = 0.90483741803595957;  // exp(-1/10)
constexpr double CE = 0.27182818284590452;  // e/10
constexpr double SC39 = 549755813888.0;     // 2^39
constexpr double INV39 = 1.0 / 549755813888.0;

// workspace byte offsets
constexpr size_t OFF_M1 = 0;                                  // u32 [B*T][28]
constexpr size_t OFF_M2 = OFF_M1 + (size_t)B * T * 28 * 4;    // u32 [B*T][16][14]
constexpr size_t OFF_S4 = OFF_M2 + (size_t)B * T * 224 * 4;   // u8  [B*T][1568]
constexpr size_t OFF_D5 = OFF_S4 + (size_t)B * T * 1568;      // f64 [B*T][410]
constexpr size_t OFF_S5 = OFF_D5 + (size_t)B * T * 410 * 8;   // u8  [B*T][410]
constexpr size_t OFF_D6 = OFF_S5 + (size_t)B * T * 410;       // f64 [B*T][10]
constexpr size_t OFF_WT = OFF_D6 + (size_t)B * T * 10 * 8;    // f32 [1568][410]
// A_pack aliases the d5 region: written by k_limbs, read by k_conv2m, both
// complete before k_dense1 writes d5 (stream-ordered).  102,400 B.
constexpr size_t OFF_AP = OFF_D5;
}  // namespace

using i32x4 = __attribute__((ext_vector_type(4))) int;
using i32x16 = __attribute__((ext_vector_type(16))) int;

// Stage 0: rate encode + bit-pack rows.  Thread per (b,y,t); loops x.
__global__ void k_encode_pack(const float* __restrict__ img, const float* __restrict__ ru,
                              unsigned int* __restrict__ m1) {
  int i = blockIdx.x * 256 + threadIdx.x;
  if (i >= B * 28 * T) return;
  int t = i % T;
  int y = (i / T) % 28;
  int b = i / (T * 28);
  unsigned int m = 0;
  const float* rb = ru + ((size_t)b * 784 + y * 28) * T + t;
  const float* ib = img + b * 784 + y * 28;
  for (int x = 0; x < 28; x++) {
    m |= (rb[(size_t)x * T] < ib[x]) ? (1u << x) : 0u;
  }
  m1[((size_t)b * T + t) * 28 + y] = m;
}

// Stage 1 fused: conv1 (1->16,5x5,pad2) + psp + spike + pool2 + psp + spike.
// (unchanged from R3)
__global__ __launch_bounds__(256) void k_conv1(const unsigned int* __restrict__ m1,
                                               const float* __restrict__ w1,
                                               unsigned int* __restrict__ m2) {
  __shared__ double lut[160];            // [dy][32]
  __shared__ unsigned int mrow[2][32];   // rows iy=-2..29 at idx iy+2; guards 0
  __shared__ unsigned char spk[784];
  __shared__ unsigned char spkP[2][196];
  int o = blockIdx.x % 16, b = blockIdx.x / 16;
  int tid = threadIdx.x;
  if (tid < 160) {
    int dy = tid / 32, f = tid % 32;
    double v = 0.0;
    const float* wb = w1 + o * 25 + dy * 5;
#pragma unroll
    for (int dx = 0; dx < 5; dx++)
      if ((f >> dx) & 1) v += (double)wb[dx];
    lut[tid] = v;
  }
  if (tid < 32) {
    mrow[0][tid] = 0;
    mrow[1][tid] = 0;
  }
  int y = tid / 7, xg = tid % 7;
  int py = tid / 14, px = tid % 14;
  bool act = tid < 196;
  double g1[4] = {0, 0, 0, 0}, g2[4] = {0, 0, 0, 0};
  double p1 = 0.0, p2 = 0.0;
  const unsigned int* m1b = m1 + (size_t)b * T * 28;
  if (tid < 28) mrow[0][tid + 2] = m1b[tid] << 2;
  __syncthreads();
  for (int t = 0; t < T; t++) {
    int cur = t & 1, nxt = cur ^ 1;
    bool dold = (tid < 28) && (t + 1 < T);
    unsigned int ldv = 0;
    if (dold) ldv = m1b[(t + 1) * 28 + tid] << 2;
    if (act) {
      double s0 = 0, s1 = 0, s2 = 0, s3 = 0;
      int xb = xg * 4;
      const unsigned int* mc = mrow[cur];
#pragma unroll
      for (int dy = 0; dy < 5; dy++) {
        unsigned int m = mc[y + dy];
        const double* ld = lut + dy * 32;
        s0 += ld[(m >> (xb + 0)) & 31];
        s1 += ld[(m >> (xb + 1)) & 31];
        s2 += ld[(m >> (xb + 2)) & 31];
        s3 += ld[(m >> (xb + 3)) & 31];
      }
      g1[0] = s0 + A1 * g1[0]; g2[0] = g1[0] + A1 * g2[0];
      g1[1] = s1 + A1 * g1[1]; g2[1] = g1[1] + A1 * g2[1];
      g1[2] = s2 + A1 * g1[2]; g2[2] = g1[2] + A1 * g2[2];
      g1[3] = s3 + A1 * g1[3]; g2[3] = g1[3] + A1 * g2[3];
      unsigned char* sp = spk + y * 28 + xb;
      sp[0] = (CE * (g2[0] - g1[0]) >= 1.0) ? 1 : 0;
      sp[1] = (CE * (g2[1] - g1[1]) >= 1.0) ? 1 : 0;
      sp[2] = (CE * (g2[2] - g1[2]) >= 1.0) ? 1 : 0;
      sp[3] = (CE * (g2[3] - g1[3]) >= 1.0) ? 1 : 0;
    }
    if (dold) mrow[nxt][tid + 2] = ldv;
    __syncthreads();
    if (act) {
      const unsigned char* r0 = spk + (2 * py) * 28 + 2 * px;
      int sum = (int)r0[0] + (int)r0[1] + (int)r0[28] + (int)r0[29];
      double s = 1.1 * (double)sum;
      p1 = s + A1 * p1;
      p2 = p1 + A1 * p2;
      spkP[cur][tid] = (CE * (p2 - p1) >= 1.0) ? 1 : 0;
    }
    if (tid < 14 && t > 0) {
      unsigned int m = 0;
      const unsigned char* rp = spkP[nxt] + tid * 14;
#pragma unroll
      for (int xx = 0; xx < 14; xx++) m |= ((unsigned int)rp[xx]) << xx;
      m2[((size_t)(b * T + (t - 1)) * 16 + o) * 14 + tid] = m;
    }
    __syncthreads();
  }
  if (tid < 14) {
    unsigned int m = 0;
    const unsigned char* rp = spkP[(T - 1) & 1] + tid * 14;
#pragma unroll
    for (int xx = 0; xx < 14; xx++) m |= ((unsigned int)rp[xx]) << xx;
    m2[((size_t)(b * T + (T - 1)) * 16 + o) * 14 + tid] = m;
  }
}

// Decompose w2 into 5 signed base-256 digits of round(w*2^39), laid out as
// MFMA A-fragments.  k' = (g<<3)+dx with g = 4c + 2eh + kh; row o = lane&31.
// AP[(((j*20 + c)*64 + lane)*16 + e)], lane = kh*32+o, e = eh*8+dx.
__global__ void k_limbs(const float* __restrict__ w2, signed char* __restrict__ AP) {
  int i = blockIdx.x * 256 + threadIdx.x;
  if (i >= 32 * 80 * 8) return;
  int dx = i & 7;
  int g = (i >> 3) % 80;
  int o = i / 640;
  int c = g >> 2, r = g & 3, eh = r >> 1, kh = r & 1;
  int lane = kh * 32 + o, e = eh * 8 + dx;
  int ci = g / 5, dy = g % 5;
  float wv = (dx < 5) ? w2[((o * 16 + ci) * 5 + dy) * 5 + dx] : 0.0f;
  long long m = llrint((double)wv * SC39);
#pragma unroll
  for (int j = 0; j < 5; j++) {
    int d = (int)((m + 128) & 255) - 128;
    AP[(size_t)((j * 20 + c) * 64 + lane) * 16 + e] = (signed char)d;
    m = (m - d) >> 8;
  }
}

// Stage 3 fused via exact i8 MFMA: conv2 + psp + spike + pool2 + psp + spike.
// Block = (b, row-pair yp): 4 waves; wave w = limb w (20 K-chunks) + 5 chunks
// of limb 4.  B built in-register from mask planes; limbs recombined exactly
// in f64; IIR+spike; 2x2 pool is in-block (row pair).
__global__ __launch_bounds__(256, 1) void k_conv2m(const unsigned int* __restrict__ m2,
                                                   const signed char* __restrict__ AP,
                                                   unsigned char* __restrict__ s4) {
  __shared__ unsigned int mrowP[2][160];  // [buf][H*80 + g]: plane word per group
  __shared__ long long Dll[8][528];       // slots 0-3 limb tiles, 4-7 limb4 partials
  __shared__ unsigned char spk2[2][896];  // [buf][o*28 + i]
  int yp = blockIdx.x % 7, b = blockIdx.x / 7;
  int y0 = yp * 2;
  int tid = threadIdx.x;
  int w = tid >> 6, l = tid & 63;
  int col = l & 31, kh = l >> 5;

  // ---- A preload (static over t): 20 main chunks + 5 limb-4 chunks ----
  const i32x4* APv = (const i32x4*)AP;
  i32x4 Aw[20], A4[5];
#pragma unroll
  for (int c = 0; c < 20; c++) Aw[c] = APv[(w * 20 + c) * 64 + l];
#pragma unroll
  for (int q = 0; q < 5; q++) A4[q] = APv[(80 + 5 * w + q) * 64 + l];

  // ---- B-builder lane constants ----
  int x = col % 14;
  unsigned int wmask = (col < 28) ? 31u : 0u;  // pad cols 28..31 contribute 0
  int half = (col >= 14) ? 1 : 0;

  // ---- staging constants (tid<160): plane word -> m2 index or -1 ----
  int stIdx = -1;
  if (tid < 160) {
    int H = tid / 80, g = tid % 80;
    int ci = g / 5, rowIdx = H + g % 5;
    int iy = y0 - 2 + rowIdx;
    if (iy >= 0 && iy < 14) stIdx = ci * 14 + iy;
  }

  // ---- reduce/IIR mapping: pairs p = (o2,i), rows 2o2,2o2+1 ----
  int o2A = tid / 28, iA = tid % 28;
  bool hasB = tid < 192;
  int o2B = (tid + 256) / 28, iB = (tid + 256) % 28;
  double g1[4] = {0, 0, 0, 0}, g2[4] = {0, 0, 0, 0};

  // ---- pool mapping (tid<224) ----
  int po = tid / 7, pxx = tid % 7;
  bool pact = tid < 224;
  double p1 = 0.0, p2 = 0.0;

  const unsigned int* m2b = m2 + (size_t)b * T * 224;
  // prestage t=0
  if (tid < 160) {
    unsigned int v = 0;
    if (stIdx >= 0) v = m2b[stIdx] << 2;
    mrowP[0][tid] = v;
  }
  __syncthreads();

  for (int t = 0; t < T; t++) {
    int cur = t & 1, nxt = cur ^ 1;
    // issue next-t global loads early (hidden under MFMA phase)
    unsigned int stv = 0;
    bool dost = (tid < 160) && (t + 1 < T);
    if (dost && stIdx >= 0) stv = m2b[(size_t)(t + 1) * 224 + stIdx] << 2;

    const unsigned int* pl = mrowP[cur] + half * 80 + kh;
    i32x16 accW, acc4;
#pragma unroll
    for (int r = 0; r < 16; r++) { accW[r] = 0; acc4[r] = 0; }

    // main K loop: wave w's own limb
#pragma unroll
    for (int c = 0; c < 20; c++) {
      unsigned int ra = pl[4 * c];      // eh=0 group
      unsigned int rb = pl[4 * c + 2];  // eh=1 group
      unsigned int w5a = (ra >> x) & wmask;
      unsigned int w5b = (rb >> x) & wmask;
      i32x4 bb;
      bb[0] = (int)(((w5a & 15u) * 0x204081u) & 0x01010101u);
      bb[1] = (int)((w5a >> 4) & 1u);
      bb[2] = (int)(((w5b & 15u) * 0x204081u) & 0x01010101u);
      bb[3] = (int)((w5b >> 4) & 1u);
      accW = __builtin_amdgcn_mfma_i32_32x32x32_i8(Aw[c], bb, accW, 0, 0, 0);
    }
    // limb-4 slice: chunks 5w..5w+4
#pragma unroll
    for (int q = 0; q < 5; q++) {
      int c4 = 5 * w + q;
      unsigned int ra = pl[4 * c4];
      unsigned int rb = pl[4 * c4 + 2];
      unsigned int w5a = (ra >> x) & wmask;
      unsigned int w5b = (rb >> x) & wmask;
      i32x4 bb;
      bb[0] = (int)(((w5a & 15u) * 0x204081u) & 0x01010101u);
      bb[1] = (int)((w5a >> 4) & 1u);
      bb[2] = (int)(((w5b & 15u) * 0x204081u) & 0x01010101u);
      bb[3] = (int)((w5b >> 4) & 1u);
      acc4 = __builtin_amdgcn_mfma_i32_32x32x32_i8(A4[q], bb, acc4, 0, 0, 0);
    }
    if (dost) mrowP[nxt][tid] = stv;

    // D writes: rows R=(r&3)+8*(r>>2)+4*kh; pairs (r,r+1) -> b64
#pragma unroll
    for (int r = 0; r < 16; r += 2) {
      int R = (r & 3) + 8 * (r >> 2) + 4 * kh;
      long long vW = (long long)(unsigned int)accW[r] | ((long long)accW[r + 1] << 32);
      long long v4 = (long long)(unsigned int)acc4[r] | ((long long)acc4[r + 1] << 32);
      Dll[w][(R >> 1) * 33 + col] = vW;
      Dll[4 + w][(R >> 1) * 33 + col] = v4;
    }
    __syncthreads();  // B1: D tiles + next masks staged

    // reduce limbs exactly in f64 + IIR + spike
#pragma unroll
    for (int pp = 0; pp < 2; pp++) {
      if (pp == 1 && !hasB) break;
      int o2 = pp ? o2B : o2A;
      int ii = pp ? iB : iA;
      int idx = o2 * 33 + ii;
      long long q0 = Dll[0][idx], q1 = Dll[1][idx], q2 = Dll[2][idx], q3 = Dll[3][idx];
      long long q4 = Dll[4][idx], q5 = Dll[5][idx], q6 = Dll[6][idx], q7 = Dll[7][idx];
      int a0 = (int)q0, a1 = (int)q1, a2 = (int)q2, a3 = (int)q3;
      int a4 = (int)q4 + (int)q5 + (int)q6 + (int)q7;
      int b0 = (int)(q0 >> 32), b1 = (int)(q1 >> 32), b2 = (int)(q2 >> 32), b3 = (int)(q3 >> 32);
      int b4 = (int)(q4 >> 32) + (int)(q5 >> 32) + (int)(q6 >> 32) + (int)(q7 >> 32);
      double sa = ((((double)a4 * 256.0 + (double)a3) * 256.0 + (double)a2) * 256.0 +
                   (double)a1) * 256.0 + (double)a0;
      double sb = ((((double)b4 * 256.0 + (double)b3) * 256.0 + (double)b2) * 256.0 +
                   (double)b1) * 256.0 + (double)b0;
      sa *= INV39;
      sb *= INV39;
      int sA = pp * 2, sB = pp * 2 + 1;
      g1[sA] = sa + A1 * g1[sA]; g2[sA] = g1[sA] + A1 * g2[sA];
      g1[sB] = sb + A1 * g1[sB]; g2[sB] = g1[sB] + A1 * g2[sB];
      spk2[cur][(2 * o2) * 28 + ii] = (CE * (g2[sA] - g1[sA]) >= 1.0) ? 1 : 0;
      spk2[cur][(2 * o2 + 1) * 28 + ii] = (CE * (g2[sB] - g1[sB]) >= 1.0) ? 1 : 0;
    }
    __syncthreads();  // B2: spikes ready; Dll free for t+1

    if (pact) {
      const unsigned char* sp = spk2[cur] + po * 28 + 2 * pxx;
      int sum = (int)sp[0] + (int)sp[1] + (int)sp[14] + (int)sp[15];
      double s = 1.1 * (double)sum;
      p1 = s + A1 * p1;
      p2 = p1 + A1 * p2;
      s4[(size_t)(b * T + t) * 1568 + po * 49 + yp * 7 + pxx] =
          (CE * (p2 - p1) >= 1.0) ? 1 : 0;
    }
  }
}

// Transpose wf1 [410][1568] -> wt [1568][410] for coalesced dense1 reads.
__global__ void k_transpose(const float* __restrict__ wf1, float* __restrict__ wt) {
  int i = blockIdx.x * 256 + threadIdx.x;
  if (i >= 410 * 1568) return;
  int col = i % 410, row = i / 410;
  wt[i] = wf1[col * 1568 + row];
}

// Stage 5a: dense1 matmul.  Block = 64 o-lanes x 4 bt-groups; 16 (b,t) columns in LDS.
__global__ __launch_bounds__(256) void k_dense1(const unsigned char* __restrict__ s4,
                                                const float* __restrict__ wt,
                                                double* __restrict__ d5) {
  __shared__ unsigned char sl[16 * 1568];  // 25088 B
  int obase = blockIdx.x * 64;   // gridDim.x = 7
  int btbase = blockIdx.y * 16;  // gridDim.y = 200
  int tid = threadIdx.x;
  int olane = tid % 64, bts = tid / 64;
  const unsigned int* src = (const unsigned int*)(s4 + (size_t)btbase * 1568);
  unsigned int* dst = (unsigned int*)sl;
  for (int k = tid; k < 6272; k += 256) dst[k] = src[k];
  __syncthreads();
  int o = obase + olane;
  bool store = o < 410;
  int osafe = store ? o : 409;
  double a0 = 0.0, a1 = 0.0, a2 = 0.0, a3 = 0.0;
  const unsigned char* c0 = sl + (bts * 4 + 0) * 1568;
  const unsigned char* c1 = sl + (bts * 4 + 1) * 1568;
  const unsigned char* c2 = sl + (bts * 4 + 2) * 1568;
  const unsigned char* c3 = sl + (bts * 4 + 3) * 1568;
  for (int i = 0; i < 1568; i++) {
    double wv = (double)wt[(size_t)i * 410 + osafe];
    a0 += wv * (double)c0[i];
    a1 += wv * (double)c1[i];
    a2 += wv * (double)c2[i];
    a3 += wv * (double)c3[i];
  }
  if (store) {
    d5[(size_t)(btbase + bts * 4 + 0) * 410 + o] = a0;
    d5[(size_t)(btbase + bts * 4 + 1) * 410 + o] = a1;
    d5[(size_t)(btbase + bts * 4 + 2) * 410 + o] = a2;
    d5[(size_t)(btbase + bts * 4 + 3) * 410 + o] = a3;
  }
}

// Stage 5b: psp + spike over dense1 output.  One thread per (b,o).
__global__ void k_psp5(const double* __restrict__ d5, unsigned char* __restrict__ s5) {
  int tid = blockIdx.x * 256 + threadIdx.x;
  if (tid >= B * 410) return;
  int o = tid % 410, b = tid / 410;
  double g1 = 0.0, g2 = 0.0;
  for (int t = 0; t < T; t++) {
    double s = d5[(size_t)(b * T + t) * 410 + o];
    g1 = s + A1 * g1;
    g2 = g1 + A1 * g2;
    s5[(size_t)(b * T + t) * 410 + o] = (CE * (g2 - g1) >= 1.0) ? 1 : 0;
  }
}

// Stage 6a: dense2 matmul.  One thread per (bt,o).
__global__ void k_dense2(const unsigned char* __restrict__ s5, const float* __restrict__ wf2,
                         double* __restrict__ d6) {
  int tid = blockIdx.x * 256 + threadIdx.x;
  if (tid >= B * T * 10) return;
  int o = tid % 10, bt = tid / 10;
  const unsigned char* sr = s5 + (size_t)bt * 410;
  const float* wr = wf2 + o * 410;
  double s = 0.0;
  for (int i = 0; i < 410; i++) s += (double)wr[i] * (double)sr[i];
  d6[tid] = s;
}

// Stage 6b: final psp + spike -> d_out [b][o][t] f32.
__global__ void k_psp6(const double* __restrict__ d6, float* __restrict__ out) {
  int tid = blockIdx.x * 256 + threadIdx.x;
  if (tid >= B * 10) return;
  int o = tid % 10, b = tid / 10;
  double g1 = 0.0, g2 = 0.0;
  for (int t = 0; t < T; t++) {
    double s = d6[(size_t)(b * T + t) * 10 + o];
    g1 = s + A1 * g1;
    g2 = g1 + A1 * g2;
    out[(size_t)b * 1000 + o * 100 + t] = (CE * (g2 - g1) >= 1.0) ? 1.0f : 0.0f;
  }
}

extern "C" void kernel_launch(void* const* d_in, const int* in_sizes, int n_in,
                              void* d_out, int out_size, void* d_ws, size_t ws_size,
                              hipStream_t stream) {
  const float* img = (const float*)d_in[0];
  const float* ru = (const float*)d_in[1];
  const float* w1 = (const float*)d_in[2];
  const float* w2 = (const float*)d_in[3];
  const float* wf1 = (const float*)d_in[4];
  const float* wf2 = (const float*)d_in[5];

  unsigned char* ws = (unsigned char*)d_ws;
  unsigned int* m1 = (unsigned int*)(ws + OFF_M1);
  unsigned int* m2 = (unsigned int*)(ws + OFF_M2);
  unsigned char* s4 = ws + OFF_S4;
  double* d5 = (double*)(ws + OFF_D5);
  unsigned char* s5 = ws + OFF_S5;
  double* d6 = (double*)(ws + OFF_D6);
  float* wt = (float*)(ws + OFF_WT);
  signed char* AP = (signed char*)(ws + OFF_AP);  // aliases d5 (freed before dense1)
  float* out = (float*)d_out;

  k_encode_pack<<<(B * 28 * T + 255) / 256, 256, 0, stream>>>(img, ru, m1);
  k_transpose<<<(410 * 1568 + 255) / 256, 256, 0, stream>>>(wf1, wt);
  k_limbs<<<(32 * 80 * 8 + 255) / 256, 256, 0, stream>>>(w2, AP);
  k_conv1<<<B * 16, 256, 0, stream>>>(m1, w1, m2);
  k_conv2m<<<B * 7, 256, 0, stream>>>(m2, AP, s4);
  k_dense1<<<dim3(7, 200), 256, 0, stream>>>(s4, wt, d5);
  k_psp5<<<(B * 410 + 255) / 256, 256, 0, stream>>>(d5, s5);
  k_dense2<<<(B * T * 10 + 255) / 256, 256, 0, stream>>>(s5, wf2, d6);
  k_psp6<<<2, 256, 0, stream>>>(d6, out);
}

// Round 4
// 467.159 us; speedup vs baseline: 1.4667x; 1.3184x over previous
//
#include <hip/hip_runtime.h>

// ---------------------------------------------------------------------------
// SLAYER-style spiking CNN forward pass, MI355X.  Round 5 (resubmit; R5 bench
// failed on GPU acquisition timeout — never measured).
//
// psp (SRM alpha kernel) as double-exponential IIR cascade (exact):
//   g1[t] = x[t] + a*g1[t-1]; g2[t] = g1[t] + a*g2[t-1]; u = (e/tau)*(g2-g1)
//
// R5: dense1 rewritten as exact integer MFMA GEMM (k_limbs2 + k_dense1m).
//   R4's k_dense1 was f64-VALU-issue-bound (232 us, model match).  Same
//   exact limb scheme as conv2m: wf1 -> 5 signed base-256 digits of
//   round(w*2^39), i8 MFMA -> exact i32, f64 limb recombine (terms < 2^50,
//   exact).  A = spike bytes loaded DIRECTLY from s4 (k-permutation
//   k = kh*16+e makes the A-fragment one 16B load; permutation applied
//   equally to A and B cancels).  Orientation A=spikes/B=weights gives
//   coalesced d5 stores.  k_transpose + wt eliminated (BP reuses slot).
// ---------------------------------------------------------------------------

namespace {
constexpr int B = 32, T = 100;
constexpr double A1 = 0.90483741803595957;  // exp(-1/10)
constexpr double CE = 0.27182818284590452;  // e/10
constexpr double SC39 = 549755813888.0;     // 2^39
constexpr double INV39 = 1.0 / 549755813888.0;

// workspace byte offsets
constexpr size_t OFF_M1 = 0;                                  // u32 [B*T][28]
constexpr size_t OFF_M2 = OFF_M1 + (size_t)B * T * 28 * 4;    // u32 [B*T][16][14]
constexpr size_t OFF_S4 = OFF_M2 + (size_t)B * T * 224 * 4;   // u8  [B*T][1568]
constexpr size_t OFF_D5 = OFF_S4 + (size_t)B * T * 1568;      // f64 [B*T][410]
constexpr size_t OFF_S5 = OFF_D5 + (size_t)B * T * 410 * 8;   // u8  [B*T][410]
constexpr size_t OFF_D6 = OFF_S5 + (size_t)B * T * 410;       // f64 [B*T][10]
constexpr size_t OFF_BP = OFF_D6 + (size_t)B * T * 10 * 8;    // i8  [13][5][49][64][16]
// A_pack (conv2 limbs) aliases the d5 region: written by k_limbs, read by
// k_conv2m, both complete before k_dense1m writes d5 (stream-ordered).
constexpr size_t OFF_AP = OFF_D5;
}  // namespace

using i32x4 = __attribute__((ext_vector_type(4))) int;
using i32x16 = __attribute__((ext_vector_type(16))) int;

// Stage 0: rate encode + bit-pack rows.  Thread per (b,y,t); loops x.
__global__ void k_encode_pack(const float* __restrict__ img, const float* __restrict__ ru,
                              unsigned int* __restrict__ m1) {
  int i = blockIdx.x * 256 + threadIdx.x;
  if (i >= B * 28 * T) return;
  int t = i % T;
  int y = (i / T) % 28;
  int b = i / (T * 28);
  unsigned int m = 0;
  const float* rb = ru + ((size_t)b * 784 + y * 28) * T + t;
  const float* ib = img + b * 784 + y * 28;
  for (int x = 0; x < 28; x++) {
    m |= (rb[(size_t)x * T] < ib[x]) ? (1u << x) : 0u;
  }
  m1[((size_t)b * T + t) * 28 + y] = m;
}

// Stage 1 fused: conv1 (1->16,5x5,pad2) + psp + spike + pool2 + psp + spike.
// (unchanged from R3)
__global__ __launch_bounds__(256) void k_conv1(const unsigned int* __restrict__ m1,
                                               const float* __restrict__ w1,
                                               unsigned int* __restrict__ m2) {
  __shared__ double lut[160];            // [dy][32]
  __shared__ unsigned int mrow[2][32];   // rows iy=-2..29 at idx iy+2; guards 0
  __shared__ unsigned char spk[784];
  __shared__ unsigned char spkP[2][196];
  int o = blockIdx.x % 16, b = blockIdx.x / 16;
  int tid = threadIdx.x;
  if (tid < 160) {
    int dy = tid / 32, f = tid % 32;
    double v = 0.0;
    const float* wb = w1 + o * 25 + dy * 5;
#pragma unroll
    for (int dx = 0; dx < 5; dx++)
      if ((f >> dx) & 1) v += (double)wb[dx];
    lut[tid] = v;
  }
  if (tid < 32) {
    mrow[0][tid] = 0;
    mrow[1][tid] = 0;
  }
  int y = tid / 7, xg = tid % 7;
  int py = tid / 14, px = tid % 14;
  bool act = tid < 196;
  double g1[4] = {0, 0, 0, 0}, g2[4] = {0, 0, 0, 0};
  double p1 = 0.0, p2 = 0.0;
  const unsigned int* m1b = m1 + (size_t)b * T * 28;
  if (tid < 28) mrow[0][tid + 2] = m1b[tid] << 2;
  __syncthreads();
  for (int t = 0; t < T; t++) {
    int cur = t & 1, nxt = cur ^ 1;
    bool dold = (tid < 28) && (t + 1 < T);
    unsigned int ldv = 0;
    if (dold) ldv = m1b[(t + 1) * 28 + tid] << 2;
    if (act) {
      double s0 = 0, s1 = 0, s2 = 0, s3 = 0;
      int xb = xg * 4;
      const unsigned int* mc = mrow[cur];
#pragma unroll
      for (int dy = 0; dy < 5; dy++) {
        unsigned int m = mc[y + dy];
        const double* ld = lut + dy * 32;
        s0 += ld[(m >> (xb + 0)) & 31];
        s1 += ld[(m >> (xb + 1)) & 31];
        s2 += ld[(m >> (xb + 2)) & 31];
        s3 += ld[(m >> (xb + 3)) & 31];
      }
      g1[0] = s0 + A1 * g1[0]; g2[0] = g1[0] + A1 * g2[0];
      g1[1] = s1 + A1 * g1[1]; g2[1] = g1[1] + A1 * g2[1];
      g1[2] = s2 + A1 * g1[2]; g2[2] = g1[2] + A1 * g2[2];
      g1[3] = s3 + A1 * g1[3]; g2[3] = g1[3] + A1 * g2[3];
      unsigned char* sp = spk + y * 28 + xb;
      sp[0] = (CE * (g2[0] - g1[0]) >= 1.0) ? 1 : 0;
      sp[1] = (CE * (g2[1] - g1[1]) >= 1.0) ? 1 : 0;
      sp[2] = (CE * (g2[2] - g1[2]) >= 1.0) ? 1 : 0;
      sp[3] = (CE * (g2[3] - g1[3]) >= 1.0) ? 1 : 0;
    }
    if (dold) mrow[nxt][tid + 2] = ldv;
    __syncthreads();
    if (act) {
      const unsigned char* r0 = spk + (2 * py) * 28 + 2 * px;
      int sum = (int)r0[0] + (int)r0[1] + (int)r0[28] + (int)r0[29];
      double s = 1.1 * (double)sum;
      p1 = s + A1 * p1;
      p2 = p1 + A1 * p2;
      spkP[cur][tid] = (CE * (p2 - p1) >= 1.0) ? 1 : 0;
    }
    if (tid < 14 && t > 0) {
      unsigned int m = 0;
      const unsigned char* rp = spkP[nxt] + tid * 14;
#pragma unroll
      for (int xx = 0; xx < 14; xx++) m |= ((unsigned int)rp[xx]) << xx;
      m2[((size_t)(b * T + (t - 1)) * 16 + o) * 14 + tid] = m;
    }
    __syncthreads();
  }
  if (tid < 14) {
    unsigned int m = 0;
    const unsigned char* rp = spkP[(T - 1) & 1] + tid * 14;
#pragma unroll
    for (int xx = 0; xx < 14; xx++) m |= ((unsigned int)rp[xx]) << xx;
    m2[((size_t)(b * T + (T - 1)) * 16 + o) * 14 + tid] = m;
  }
}

// conv2 weight limbs: 5 signed base-256 digits of round(w2*2^39), laid out as
// MFMA A-fragments.  k' = (g<<3)+dx with g = 4c + 2eh + kh; row o = lane&31.
__global__ void k_limbs(const float* __restrict__ w2, signed char* __restrict__ AP) {
  int i = blockIdx.x * 256 + threadIdx.x;
  if (i >= 32 * 80 * 8) return;
  int dx = i & 7;
  int g = (i >> 3) % 80;
  int o = i / 640;
  int c = g >> 2, r = g & 3, eh = r >> 1, kh = r & 1;
  int lane = kh * 32 + o, e = eh * 8 + dx;
  int ci = g / 5, dy = g % 5;
  float wv = (dx < 5) ? w2[((o * 16 + ci) * 5 + dy) * 5 + dx] : 0.0f;
  long long m = llrint((double)wv * SC39);
#pragma unroll
  for (int j = 0; j < 5; j++) {
    int d = (int)((m + 128) & 255) - 128;
    AP[(size_t)((j * 20 + c) * 64 + lane) * 16 + e] = (signed char)d;
    m = (m - d) >> 8;
  }
}

// Stage 3 fused via exact i8 MFMA: conv2 + psp + spike + pool2 + psp + spike.
// (unchanged from R4)
__global__ __launch_bounds__(256, 1) void k_conv2m(const unsigned int* __restrict__ m2,
                                                   const signed char* __restrict__ AP,
                                                   unsigned char* __restrict__ s4) {
  __shared__ unsigned int mrowP[2][160];  // [buf][H*80 + g]: plane word per group
  __shared__ long long Dll[8][528];       // slots 0-3 limb tiles, 4-7 limb4 partials
  __shared__ unsigned char spk2[2][896];  // [buf][o*28 + i]
  int yp = blockIdx.x % 7, b = blockIdx.x / 7;
  int y0 = yp * 2;
  int tid = threadIdx.x;
  int w = tid >> 6, l = tid & 63;
  int col = l & 31, kh = l >> 5;

  const i32x4* APv = (const i32x4*)AP;
  i32x4 Aw[20], A4[5];
#pragma unroll
  for (int c = 0; c < 20; c++) Aw[c] = APv[(w * 20 + c) * 64 + l];
#pragma unroll
  for (int q = 0; q < 5; q++) A4[q] = APv[(80 + 5 * w + q) * 64 + l];

  int x = col % 14;
  unsigned int wmask = (col < 28) ? 31u : 0u;  // pad cols 28..31 contribute 0
  int half = (col >= 14) ? 1 : 0;

  int stIdx = -1;
  if (tid < 160) {
    int H = tid / 80, g = tid % 80;
    int ci = g / 5, rowIdx = H + g % 5;
    int iy = y0 - 2 + rowIdx;
    if (iy >= 0 && iy < 14) stIdx = ci * 14 + iy;
  }

  int o2A = tid / 28, iA = tid % 28;
  bool hasB = tid < 192;
  int o2B = (tid + 256) / 28, iB = (tid + 256) % 28;
  double g1[4] = {0, 0, 0, 0}, g2[4] = {0, 0, 0, 0};

  int po = tid / 7, pxx = tid % 7;
  bool pact = tid < 224;
  double p1 = 0.0, p2 = 0.0;

  const unsigned int* m2b = m2 + (size_t)b * T * 224;
  if (tid < 160) {
    unsigned int v = 0;
    if (stIdx >= 0) v = m2b[stIdx] << 2;
    mrowP[0][tid] = v;
  }
  __syncthreads();

  for (int t = 0; t < T; t++) {
    int cur = t & 1, nxt = cur ^ 1;
    unsigned int stv = 0;
    bool dost = (tid < 160) && (t + 1 < T);
    if (dost && stIdx >= 0) stv = m2b[(size_t)(t + 1) * 224 + stIdx] << 2;

    const unsigned int* pl = mrowP[cur] + half * 80 + kh;
    i32x16 accW, acc4;
#pragma unroll
    for (int r = 0; r < 16; r++) { accW[r] = 0; acc4[r] = 0; }

#pragma unroll
    for (int c = 0; c < 20; c++) {
      unsigned int ra = pl[4 * c];
      unsigned int rb = pl[4 * c + 2];
      unsigned int w5a = (ra >> x) & wmask;
      unsigned int w5b = (rb >> x) & wmask;
      i32x4 bb;
      bb[0] = (int)(((w5a & 15u) * 0x204081u) & 0x01010101u);
      bb[1] = (int)((w5a >> 4) & 1u);
      bb[2] = (int)(((w5b & 15u) * 0x204081u) & 0x01010101u);
      bb[3] = (int)((w5b >> 4) & 1u);
      accW = __builtin_amdgcn_mfma_i32_32x32x32_i8(Aw[c], bb, accW, 0, 0, 0);
    }
#pragma unroll
    for (int q = 0; q < 5; q++) {
      int c4 = 5 * w + q;
      unsigned int ra = pl[4 * c4];
      unsigned int rb = pl[4 * c4 + 2];
      unsigned int w5a = (ra >> x) & wmask;
      unsigned int w5b = (rb >> x) & wmask;
      i32x4 bb;
      bb[0] = (int)(((w5a & 15u) * 0x204081u) & 0x01010101u);
      bb[1] = (int)((w5a >> 4) & 1u);
      bb[2] = (int)(((w5b & 15u) * 0x204081u) & 0x01010101u);
      bb[3] = (int)((w5b >> 4) & 1u);
      acc4 = __builtin_amdgcn_mfma_i32_32x32x32_i8(A4[q], bb, acc4, 0, 0, 0);
    }
    if (dost) mrowP[nxt][tid] = stv;

#pragma unroll
    for (int r = 0; r < 16; r += 2) {
      int R = (r & 3) + 8 * (r >> 2) + 4 * kh;
      long long vW = (long long)(unsigned int)accW[r] | ((long long)accW[r + 1] << 32);
      long long v4 = (long long)(unsigned int)acc4[r] | ((long long)acc4[r + 1] << 32);
      Dll[w][(R >> 1) * 33 + col] = vW;
      Dll[4 + w][(R >> 1) * 33 + col] = v4;
    }
    __syncthreads();  // B1: D tiles + next masks staged

#pragma unroll
    for (int pp = 0; pp < 2; pp++) {
      if (pp == 1 && !hasB) break;
      int o2 = pp ? o2B : o2A;
      int ii = pp ? iB : iA;
      int idx = o2 * 33 + ii;
      long long q0 = Dll[0][idx], q1 = Dll[1][idx], q2 = Dll[2][idx], q3 = Dll[3][idx];
      long long q4 = Dll[4][idx], q5 = Dll[5][idx], q6 = Dll[6][idx], q7 = Dll[7][idx];
      int a0 = (int)q0, a1 = (int)q1, a2 = (int)q2, a3 = (int)q3;
      int a4 = (int)q4 + (int)q5 + (int)q6 + (int)q7;
      int b0 = (int)(q0 >> 32), b1 = (int)(q1 >> 32), b2 = (int)(q2 >> 32), b3 = (int)(q3 >> 32);
      int b4 = (int)(q4 >> 32) + (int)(q5 >> 32) + (int)(q6 >> 32) + (int)(q7 >> 32);
      double sa = ((((double)a4 * 256.0 + (double)a3) * 256.0 + (double)a2) * 256.0 +
                   (double)a1) * 256.0 + (double)a0;
      double sb = ((((double)b4 * 256.0 + (double)b3) * 256.0 + (double)b2) * 256.0 +
                   (double)b1) * 256.0 + (double)b0;
      sa *= INV39;
      sb *= INV39;
      int sA = pp * 2, sB = pp * 2 + 1;
      g1[sA] = sa + A1 * g1[sA]; g2[sA] = g1[sA] + A1 * g2[sA];
      g1[sB] = sb + A1 * g1[sB]; g2[sB] = g1[sB] + A1 * g2[sB];
      spk2[cur][(2 * o2) * 28 + ii] = (CE * (g2[sA] - g1[sA]) >= 1.0) ? 1 : 0;
      spk2[cur][(2 * o2 + 1) * 28 + ii] = (CE * (g2[sB] - g1[sB]) >= 1.0) ? 1 : 0;
    }
    __syncthreads();  // B2: spikes ready; Dll free for t+1

    if (pact) {
      const unsigned char* sp = spk2[cur] + po * 28 + 2 * pxx;
      int sum = (int)sp[0] + (int)sp[1] + (int)sp[14] + (int)sp[15];
      double s = 1.1 * (double)sum;
      p1 = s + A1 * p1;
      p2 = p1 + A1 * p2;
      s4[(size_t)(b * T + t) * 1568 + po * 49 + yp * 7 + pxx] =
          (CE * (p2 - p1) >= 1.0) ? 1 : 0;
    }
  }
}

// dense1 weight limbs: 5 signed base-256 digits of round(wf1*2^39), packed as
// MFMA B-fragments with logical k = kh*16 + e (same permutation as the A-side
// spike load in k_dense1m; permutation cancels).
// BP[fi*64 + lane][e], fi = ot*245 + j*49 + c; value = limb_j of
// wf1[o = ot*32 + (lane&31)][i = 32c + (lane>>5)*16 + e], 0 for o >= 410.
__global__ void k_limbs2(const float* __restrict__ wf1, signed char* __restrict__ BP) {
  int i = blockIdx.x * 256 + threadIdx.x;
  if (i >= 13 * 5 * 49 * 64) return;
  int lane = i & 63;
  int fi = i >> 6;
  int c = fi % 49;
  int j = (fi / 49) % 5;
  int ot = fi / 245;
  int o = ot * 32 + (lane & 31);
  int kb = 32 * c + (lane >> 5) * 16;
  int wd[4] = {0, 0, 0, 0};
#pragma unroll
  for (int e = 0; e < 16; e++) {
    float wv = (o < 410) ? wf1[(size_t)o * 1568 + kb + e] : 0.0f;
    long long m = llrint((double)wv * SC39);
    int d = 0;
    for (int jj = 0; jj <= j; jj++) {
      d = (int)((m + 128) & 255) - 128;
      m = (m - d) >> 8;
    }
    wd[e >> 2] |= (d & 255) << ((e & 3) * 8);
  }
  i32x4 v;
  v[0] = wd[0]; v[1] = wd[1]; v[2] = wd[2]; v[3] = wd[3];
  *(i32x4*)(BP + (size_t)i * 16) = v;
}

// Stage 5a: dense1 as exact i8-limb MFMA GEMM.
// Grid (25, 13): x -> group of 4 bt-tiles (one per wave), y -> o-tile.
// A = spike bytes (M=bt), one 16B load per chunk; B = weight limbs (N=o).
// D: row bt = (r&3)+8*(r>>2)+4*kh, col o = lane&31 -> coalesced d5 stores.
__global__ __launch_bounds__(256) void k_dense1m(const unsigned char* __restrict__ s4,
                                                 const signed char* __restrict__ BP,
                                                 double* __restrict__ d5) {
  int ot = blockIdx.y;
  int w = threadIdx.x >> 6, l = threadIdx.x & 63;
  int col = l & 31, kh = l >> 5;
  int btTile = blockIdx.x * 4 + w;
  const unsigned char* arow = s4 + (size_t)(btTile * 32 + col) * 1568 + kh * 16;
  const i32x4* bpv = (const i32x4*)BP + (size_t)ot * 245 * 64 + l;
  i32x16 acc0, acc1, acc2, acc3, acc4;
#pragma unroll
  for (int r = 0; r < 16; r++) {
    acc0[r] = 0; acc1[r] = 0; acc2[r] = 0; acc3[r] = 0; acc4[r] = 0;
  }
  for (int c = 0; c < 49; c++) {
    i32x4 a = *(const i32x4*)(arow + 32 * c);
    i32x4 b0 = bpv[(0 * 49 + c) * 64];
    i32x4 b1 = bpv[(1 * 49 + c) * 64];
    i32x4 b2 = bpv[(2 * 49 + c) * 64];
    i32x4 b3 = bpv[(3 * 49 + c) * 64];
    i32x4 b4 = bpv[(4 * 49 + c) * 64];
    acc0 = __builtin_amdgcn_mfma_i32_32x32x32_i8(a, b0, acc0, 0, 0, 0);
    acc1 = __builtin_amdgcn_mfma_i32_32x32x32_i8(a, b1, acc1, 0, 0, 0);
    acc2 = __builtin_amdgcn_mfma_i32_32x32x32_i8(a, b2, acc2, 0, 0, 0);
    acc3 = __builtin_amdgcn_mfma_i32_32x32x32_i8(a, b3, acc3, 0, 0, 0);
    acc4 = __builtin_amdgcn_mfma_i32_32x32x32_i8(a, b4, acc4, 0, 0, 0);
  }
  int o = ot * 32 + col;
  if (o < 410) {
#pragma unroll
    for (int r = 0; r < 16; r++) {
      int R = (r & 3) + 8 * (r >> 2) + 4 * kh;
      double v = ((((double)acc4[r] * 256.0 + (double)acc3[r]) * 256.0 +
                   (double)acc2[r]) * 256.0 + (double)acc1[r]) * 256.0 + (double)acc0[r];
      d5[(size_t)(btTile * 32 + R) * 410 + o] = v * INV39;
    }
  }
}

// Stage 5b: psp + spike over dense1 output.  One thread per (b,o).
__global__ void k_psp5(const double* __restrict__ d5, unsigned char* __restrict__ s5) {
  int tid = blockIdx.x * 256 + threadIdx.x;
  if (tid >= B * 410) return;
  int o = tid % 410, b = tid / 410;
  double g1 = 0.0, g2 = 0.0;
  for (int t = 0; t < T; t++) {
    double s = d5[(size_t)(b * T + t) * 410 + o];
    g1 = s + A1 * g1;
    g2 = g1 + A1 * g2;
    s5[(size_t)(b * T + t) * 410 + o] = (CE * (g2 - g1) >= 1.0) ? 1 : 0;
  }
}

// Stage 6a: dense2 matmul.  One thread per (bt,o).
__global__ void k_dense2(const unsigned char* __restrict__ s5, const float* __restrict__ wf2,
                         double* __restrict__ d6) {
  int tid = blockIdx.x * 256 + threadIdx.x;
  if (tid >= B * T * 10) return;
  int o = tid % 10, bt = tid / 10;
  const unsigned char* sr = s5 + (size_t)bt * 410;
  const float* wr = wf2 + o * 410;
  double s = 0.0;
  for (int i = 0; i < 410; i++) s += (double)wr[i] * (double)sr[i];
  d6[tid] = s;
}

// Stage 6b: final psp + spike -> d_out [b][o][t] f32.
__global__ void k_psp6(const double* __restrict__ d6, float* __restrict__ out) {
  int tid = blockIdx.x * 256 + threadIdx.x;
  if (tid >= B * 10) return;
  int o = tid % 10, b = tid / 10;
  double g1 = 0.0, g2 = 0.0;
  for (int t = 0; t < T; t++) {
    double s = d6[(size_t)(b * T + t) * 10 + o];
    g1 = s + A1 * g1;
    g2 = g1 + A1 * g2;
    out[(size_t)b * 1000 + o * 100 + t] = (CE * (g2 - g1) >= 1.0) ? 1.0f : 0.0f;
  }
}

extern "C" void kernel_launch(void* const* d_in, const int* in_sizes, int n_in,
                              void* d_out, int out_size, void* d_ws, size_t ws_size,
                              hipStream_t stream) {
  const float* img = (const float*)d_in[0];
  const float* ru = (const float*)d_in[1];
  const float* w1 = (const float*)d_in[2];
  const float* w2 = (const float*)d_in[3];
  const float* wf1 = (const float*)d_in[4];
  const float* wf2 = (const float*)d_in[5];

  unsigned char* ws = (unsigned char*)d_ws;
  unsigned int* m1 = (unsigned int*)(ws + OFF_M1);
  unsigned int* m2 = (unsigned int*)(ws + OFF_M2);
  unsigned char* s4 = ws + OFF_S4;
  double* d5 = (double*)(ws + OFF_D5);
  unsigned char* s5 = ws + OFF_S5;
  double* d6 = (double*)(ws + OFF_D6);
  signed char* AP = (signed char*)(ws + OFF_AP);  // aliases d5 (freed before dense1m)
  signed char* BP = (signed char*)(ws + OFF_BP);
  float* out = (float*)d_out;

  k_encode_pack<<<(B * 28 * T + 255) / 256, 256, 0, stream>>>(img, ru, m1);
  k_limbs<<<(32 * 80 * 8 + 255) / 256, 256, 0, stream>>>(w2, AP);
  k_limbs2<<<(13 * 5 * 49 * 64 + 255) / 256, 256, 0, stream>>>(wf1, BP);
  k_conv1<<<B * 16, 256, 0, stream>>>(m1, w1, m2);
  k_conv2m<<<B * 7, 256, 0, stream>>>(m2, AP, s4);
  k_dense1m<<<dim3(25, 13), 256, 0, stream>>>(s4, BP, d5);
  k_psp5<<<(B * 410 + 255) / 256, 256, 0, stream>>>(d5, s5);
  k_dense2<<<(B * T * 10 + 255) / 256, 256, 0, stream>>>(s5, wf2, d6);
  k_psp6<<<2, 256, 0, stream>>>(d6, out);
}

// Round 6
// 412.591 us; speedup vs baseline: 1.6606x; 1.1323x over previous
//
#include <hip/hip_runtime.h>

// ---------------------------------------------------------------------------
// SLAYER-style spiking CNN forward pass, MI355X.  Round 6 (resubmit; bench
// failed twice on GPU acquisition timeout — never measured).
//
// psp (SRM alpha kernel) as double-exponential IIR cascade (exact):
//   g1[t] = x[t] + a*g1[t-1]; g2[t] = g1[t] + a*g2[t-1]; u = (e/tau)*(g2-g1)
//
// R6: conv2 restructured as k_conv2t.  R5's conv2m was latency-bound at
//   1 wave/SIMD (occ 10%, 4970 cyc/t vs 200 cyc of MFMA).  New wave split:
//   (2 timesteps x 2 K-halves) per 256-thread block.  A-fragments preloaded
//   ONCE into 200 VGPRs (launch_bounds(256,1) -> 512-reg budget; grid is
//   structurally 1 block/CU so occupancy is unaffected).  Each wave computes
//   all 5 limbs for its (t, K-half), recombines in-register to an exact
//   integer f64 partial (<2^49); 2-way cross-wave f64 sum is exact ->
//   bit-identical to R4/R5.  Barriers 2 per 2-t group (was 2/t); Dll
//   exchange replaced by 2-partial exchange; B-build amortized 2.5x.
//   All other kernels unchanged from R5.
// ---------------------------------------------------------------------------

namespace {
constexpr int B = 32, T = 100;
constexpr double A1 = 0.90483741803595957;  // exp(-1/10)
constexpr double CE = 0.27182818284590452;  // e/10
constexpr double SC39 = 549755813888.0;     // 2^39
constexpr double INV39 = 1.0 / 549755813888.0;

// workspace byte offsets
constexpr size_t OFF_M1 = 0;                                  // u32 [B*T][28]
constexpr size_t OFF_M2 = OFF_M1 + (size_t)B * T * 28 * 4;    // u32 [B*T][16][14]
constexpr size_t OFF_S4 = OFF_M2 + (size_t)B * T * 224 * 4;   // u8  [B*T][1568]
constexpr size_t OFF_D5 = OFF_S4 + (size_t)B * T * 1568;      // f64 [B*T][410]
constexpr size_t OFF_S5 = OFF_D5 + (size_t)B * T * 410 * 8;   // u8  [B*T][410]
constexpr size_t OFF_D6 = OFF_S5 + (size_t)B * T * 410;       // f64 [B*T][10]
constexpr size_t OFF_BP = OFF_D6 + (size_t)B * T * 10 * 8;    // i8  [13][5][49][64][16]
// A_pack (conv2 limbs) aliases the d5 region: written by k_limbs, read by
// k_conv2t, both complete before k_dense1m writes d5 (stream-ordered).
constexpr size_t OFF_AP = OFF_D5;
}  // namespace

using i32x4 = __attribute__((ext_vector_type(4))) int;
using i32x16 = __attribute__((ext_vector_type(16))) int;

// Stage 0: rate encode + bit-pack rows.  Thread per (b,y,t); loops x.
__global__ void k_encode_pack(const float* __restrict__ img, const float* __restrict__ ru,
                              unsigned int* __restrict__ m1) {
  int i = blockIdx.x * 256 + threadIdx.x;
  if (i >= B * 28 * T) return;
  int t = i % T;
  int y = (i / T) % 28;
  int b = i / (T * 28);
  unsigned int m = 0;
  const float* rb = ru + ((size_t)b * 784 + y * 28) * T + t;
  const float* ib = img + b * 784 + y * 28;
  for (int x = 0; x < 28; x++) {
    m |= (rb[(size_t)x * T] < ib[x]) ? (1u << x) : 0u;
  }
  m1[((size_t)b * T + t) * 28 + y] = m;
}

// Stage 1 fused: conv1 (1->16,5x5,pad2) + psp + spike + pool2 + psp + spike.
// (unchanged)
__global__ __launch_bounds__(256) void k_conv1(const unsigned int* __restrict__ m1,
                                               const float* __restrict__ w1,
                                               unsigned int* __restrict__ m2) {
  __shared__ double lut[160];            // [dy][32]
  __shared__ unsigned int mrow[2][32];   // rows iy=-2..29 at idx iy+2; guards 0
  __shared__ unsigned char spk[784];
  __shared__ unsigned char spkP[2][196];
  int o = blockIdx.x % 16, b = blockIdx.x / 16;
  int tid = threadIdx.x;
  if (tid < 160) {
    int dy = tid / 32, f = tid % 32;
    double v = 0.0;
    const float* wb = w1 + o * 25 + dy * 5;
#pragma unroll
    for (int dx = 0; dx < 5; dx++)
      if ((f >> dx) & 1) v += (double)wb[dx];
    lut[tid] = v;
  }
  if (tid < 32) {
    mrow[0][tid] = 0;
    mrow[1][tid] = 0;
  }
  int y = tid / 7, xg = tid % 7;
  int py = tid / 14, px = tid % 14;
  bool act = tid < 196;
  double g1[4] = {0, 0, 0, 0}, g2[4] = {0, 0, 0, 0};
  double p1 = 0.0, p2 = 0.0;
  const unsigned int* m1b = m1 + (size_t)b * T * 28;
  if (tid < 28) mrow[0][tid + 2] = m1b[tid] << 2;
  __syncthreads();
  for (int t = 0; t < T; t++) {
    int cur = t & 1, nxt = cur ^ 1;
    bool dold = (tid < 28) && (t + 1 < T);
    unsigned int ldv = 0;
    if (dold) ldv = m1b[(t + 1) * 28 + tid] << 2;
    if (act) {
      double s0 = 0, s1 = 0, s2 = 0, s3 = 0;
      int xb = xg * 4;
      const unsigned int* mc = mrow[cur];
#pragma unroll
      for (int dy = 0; dy < 5; dy++) {
        unsigned int m = mc[y + dy];
        const double* ld = lut + dy * 32;
        s0 += ld[(m >> (xb + 0)) & 31];
        s1 += ld[(m >> (xb + 1)) & 31];
        s2 += ld[(m >> (xb + 2)) & 31];
        s3 += ld[(m >> (xb + 3)) & 31];
      }
      g1[0] = s0 + A1 * g1[0]; g2[0] = g1[0] + A1 * g2[0];
      g1[1] = s1 + A1 * g1[1]; g2[1] = g1[1] + A1 * g2[1];
      g1[2] = s2 + A1 * g1[2]; g2[2] = g1[2] + A1 * g2[2];
      g1[3] = s3 + A1 * g1[3]; g2[3] = g1[3] + A1 * g2[3];
      unsigned char* sp = spk + y * 28 + xb;
      sp[0] = (CE * (g2[0] - g1[0]) >= 1.0) ? 1 : 0;
      sp[1] = (CE * (g2[1] - g1[1]) >= 1.0) ? 1 : 0;
      sp[2] = (CE * (g2[2] - g1[2]) >= 1.0) ? 1 : 0;
      sp[3] = (CE * (g2[3] - g1[3]) >= 1.0) ? 1 : 0;
    }
    if (dold) mrow[nxt][tid + 2] = ldv;
    __syncthreads();
    if (act) {
      const unsigned char* r0 = spk + (2 * py) * 28 + 2 * px;
      int sum = (int)r0[0] + (int)r0[1] + (int)r0[28] + (int)r0[29];
      double s = 1.1 * (double)sum;
      p1 = s + A1 * p1;
      p2 = p1 + A1 * p2;
      spkP[cur][tid] = (CE * (p2 - p1) >= 1.0) ? 1 : 0;
    }
    if (tid < 14 && t > 0) {
      unsigned int m = 0;
      const unsigned char* rp = spkP[nxt] + tid * 14;
#pragma unroll
      for (int xx = 0; xx < 14; xx++) m |= ((unsigned int)rp[xx]) << xx;
      m2[((size_t)(b * T + (t - 1)) * 16 + o) * 14 + tid] = m;
    }
    __syncthreads();
  }
  if (tid < 14) {
    unsigned int m = 0;
    const unsigned char* rp = spkP[(T - 1) & 1] + tid * 14;
#pragma unroll
    for (int xx = 0; xx < 14; xx++) m |= ((unsigned int)rp[xx]) << xx;
    m2[((size_t)(b * T + (T - 1)) * 16 + o) * 14 + tid] = m;
  }
}

// conv2 weight limbs: 5 signed base-256 digits of round(w2*2^39), laid out as
// MFMA A-fragments.  k' = (g<<3)+dx with g = 4c + 2eh + kh; row o = lane&31.
// (unchanged from R4/R5 — layout verified bit-exact)
__global__ void k_limbs(const float* __restrict__ w2, signed char* __restrict__ AP) {
  int i = blockIdx.x * 256 + threadIdx.x;
  if (i >= 32 * 80 * 8) return;
  int dx = i & 7;
  int g = (i >> 3) % 80;
  int o = i / 640;
  int c = g >> 2, r = g & 3, eh = r >> 1, kh = r & 1;
  int lane = kh * 32 + o, e = eh * 8 + dx;
  int ci = g / 5, dy = g % 5;
  float wv = (dx < 5) ? w2[((o * 16 + ci) * 5 + dy) * 5 + dx] : 0.0f;
  long long m = llrint((double)wv * SC39);
#pragma unroll
  for (int j = 0; j < 5; j++) {
    int d = (int)((m + 128) & 255) - 128;
    AP[(size_t)((j * 20 + c) * 64 + lane) * 16 + e] = (signed char)d;
    m = (m - d) >> 8;
  }
}

// Stage 3 fused via exact i8 MFMA, t-interleaved: conv2 + psp + spike +
// pool2 + psp + spike.  Block = (b, row-pair yp), 4 waves = 2 t x 2 K-halves.
// Wave (tp = w>>1, kg = w&1): timestep grp*2+tp, K-chunks [10kg,10kg+10),
// ALL 5 limbs.  A preloaded once (50 frags = 200 VGPRs).  In-register limb
// recombine -> exact integer f64 partial; 2-way partial sum is exact.
__global__ __launch_bounds__(256, 1) void k_conv2t(const unsigned int* __restrict__ m2,
                                                   const signed char* __restrict__ AP,
                                                   unsigned char* __restrict__ s4) {
  // mask words, permuted so each lane's 20 words are contiguous:
  //   pos(H,g) = H*80 + (g&1)*40 + 2*(g>>2) + ((g>>1)&1)   [g = 4c+2eh+kh]
  __shared__ unsigned int maskW[2][2][176];  // [buf][slab tp][pos], 160 used
  __shared__ double part[2][2][32][30];      // [tp][kg][row o][col px], 28 used
  __shared__ unsigned char spk[2][32][28];   // [g][o][px]
  int yp = blockIdx.x % 7, b = blockIdx.x / 7;
  int y0 = yp * 2;
  int tid = threadIdx.x;
  int w = tid >> 6, l = tid & 63;
  int tp = w >> 1, kg = w & 1;
  int col = l & 31, kh = l >> 5;
  int x = col % 14;
  unsigned int wmask = (col < 28) ? 31u : 0u;
  int half = (col >= 14) ? 1 : 0;
  const unsigned int* m2b = m2 + (size_t)b * T * 224;

  // ---- A preload: limbs 0..4, chunks 10kg..10kg+9 (static over t) ----
  const i32x4* APv = (const i32x4*)AP;
  i32x4 Af[5][10];
#pragma unroll
  for (int j = 0; j < 5; j++)
#pragma unroll
    for (int cl = 0; cl < 10; cl++)
      Af[j][cl] = APv[(size_t)((j * 20) + kg * 10 + cl) * 64 + l];

  // ---- IIR / pool state ----
  double cg1[4] = {0, 0, 0, 0}, cg2[4] = {0, 0, 0, 0};
  double q1 = 0.0, q2 = 0.0;
  int to = tid / 7, pg = tid % 7;  // chain coords (tid<224): o, px-group-of-4
  bool chainAct = tid < 224;

  // ---- mask stager: waves 0,1 stage slab w for timestep base+w ----
  auto stage = [&](int buf, int baseT) {
    if (w < 2) {
      int tS = baseT + w;
#pragma unroll
      for (int pass = 0; pass < 3; pass++) {
        if (pass == 2 && l >= 32) break;
        int e = pass * 64 + l;
        int H = e / 80, g = e % 80;
        int ci = g / 5, dy = g % 5;
        int iy = y0 - 2 + H + dy;
        unsigned int v = 0;
        if (iy >= 0 && iy < 14 && tS < T) v = m2b[(size_t)tS * 224 + ci * 14 + iy] << 2;
        maskW[buf][w][H * 80 + (g & 1) * 40 + 2 * (g >> 2) + ((g >> 1) & 1)] = v;
      }
    }
  };

  stage(0, 0);
  __syncthreads();

  for (int grp = 0; grp < 50; grp++) {
    int cur = grp & 1, nxt = cur ^ 1;

    // ---- conv phase: this wave's (t = grp*2+tp, K-half kg), all limbs ----
    {
      const uint4* mwv = (const uint4*)&maskW[cur][tp][0];
      int base4 = half * 20 + kh * 10 + 5 * kg;  // uint4 index of 20-word run
      uint4 mk0 = mwv[base4 + 0], mk1 = mwv[base4 + 1], mk2 = mwv[base4 + 2];
      uint4 mk3 = mwv[base4 + 3], mk4 = mwv[base4 + 4];
      i32x16 ac0, ac1, ac2, ac3, ac4;
#pragma unroll
      for (int r = 0; r < 16; r++) { ac0[r] = 0; ac1[r] = 0; ac2[r] = 0; ac3[r] = 0; ac4[r] = 0; }
#pragma unroll
      for (int cl = 0; cl < 10; cl++) {
        uint4 mkv = (cl < 2) ? mk0 : (cl < 4) ? mk1 : (cl < 6) ? mk2 : (cl < 8) ? mk3 : mk4;
        unsigned int ra = (cl & 1) ? mkv.z : mkv.x;
        unsigned int rb = (cl & 1) ? mkv.w : mkv.y;
        unsigned int a5 = (ra >> x) & wmask;
        unsigned int b5 = (rb >> x) & wmask;
        i32x4 bb;
        bb[0] = (int)(((a5 & 15u) * 0x204081u) & 0x01010101u);
        bb[1] = (int)((a5 >> 4) & 1u);
        bb[2] = (int)(((b5 & 15u) * 0x204081u) & 0x01010101u);
        bb[3] = (int)((b5 >> 4) & 1u);
        ac0 = __builtin_amdgcn_mfma_i32_32x32x32_i8(Af[0][cl], bb, ac0, 0, 0, 0);
        ac1 = __builtin_amdgcn_mfma_i32_32x32x32_i8(Af[1][cl], bb, ac1, 0, 0, 0);
        ac2 = __builtin_amdgcn_mfma_i32_32x32x32_i8(Af[2][cl], bb, ac2, 0, 0, 0);
        ac3 = __builtin_amdgcn_mfma_i32_32x32x32_i8(Af[3][cl], bb, ac3, 0, 0, 0);
        ac4 = __builtin_amdgcn_mfma_i32_32x32x32_i8(Af[4][cl], bb, ac4, 0, 0, 0);
      }
      // exact integer limb recombine -> f64 partial (|value| < 2^49, exact)
      if (col < 28) {
#pragma unroll
        for (int r = 0; r < 16; r++) {
          int R = (r & 3) + 8 * (r >> 2) + 4 * kh;
          int c01 = ac1[r] * 256 + ac0[r];
          int c23 = ac3[r] * 256 + ac2[r];
          double S = ((double)ac4[r] * 65536.0 + (double)c23) * 65536.0 + (double)c01;
          part[tp][kg][R][col] = S;
        }
      }
    }

    stage(nxt, (grp + 1) * 2);  // masks for next group (any wave -> B1 syncs)
    __syncthreads();            // B1: partials + next masks ready

    // ---- IIR + spike (2 timesteps, in order) ----
    if (chainAct) {
#pragma unroll
      for (int g = 0; g < 2; g++) {
        const double* pa = &part[g][0][to][pg * 4];
        const double* pb = &part[g][1][to][pg * 4];
        double s0 = (pa[0] + pb[0]) * INV39;
        double s1 = (pa[1] + pb[1]) * INV39;
        double s2 = (pa[2] + pb[2]) * INV39;
        double s3 = (pa[3] + pb[3]) * INV39;
        cg1[0] = s0 + A1 * cg1[0]; cg2[0] = cg1[0] + A1 * cg2[0];
        cg1[1] = s1 + A1 * cg1[1]; cg2[1] = cg1[1] + A1 * cg2[1];
        cg1[2] = s2 + A1 * cg1[2]; cg2[2] = cg1[2] + A1 * cg2[2];
        cg1[3] = s3 + A1 * cg1[3]; cg2[3] = cg1[3] + A1 * cg2[3];
        unsigned int pk = (CE * (cg2[0] - cg1[0]) >= 1.0 ? 1u : 0u)
                        | ((CE * (cg2[1] - cg1[1]) >= 1.0 ? 1u : 0u) << 8)
                        | ((CE * (cg2[2] - cg1[2]) >= 1.0 ? 1u : 0u) << 16)
                        | ((CE * (cg2[3] - cg1[3]) >= 1.0 ? 1u : 0u) << 24);
        *(unsigned int*)&spk[g][to][pg * 4] = pk;
      }
    }
    __syncthreads();  // B2: spikes ready for pool

    // ---- pool + IIR + s4 store (2 timesteps) ----
    if (chainAct) {
      int po = to, pp = pg;
#pragma unroll
      for (int g = 0; g < 2; g++) {
        const unsigned char* sr = &spk[g][po][0];
        int sum = (int)sr[2 * pp] + (int)sr[2 * pp + 1] + (int)sr[14 + 2 * pp] + (int)sr[15 + 2 * pp];
        double s = 1.1 * (double)sum;
        q1 = s + A1 * q1;
        q2 = q1 + A1 * q2;
        s4[(size_t)(b * T + grp * 2 + g) * 1568 + po * 49 + yp * 7 + pp] =
            (CE * (q2 - q1) >= 1.0) ? 1 : 0;
      }
    }
    // next grp's conv writes part / IIR writes spk only after B1' -> safe
  }
}

// dense1 weight limbs: 5 signed base-256 digits of round(wf1*2^39), packed as
// MFMA B-fragments with logical k = kh*16 + e.  (unchanged)
__global__ void k_limbs2(const float* __restrict__ wf1, signed char* __restrict__ BP) {
  int i = blockIdx.x * 256 + threadIdx.x;
  if (i >= 13 * 5 * 49 * 64) return;
  int lane = i & 63;
  int fi = i >> 6;
  int c = fi % 49;
  int j = (fi / 49) % 5;
  int ot = fi / 245;
  int o = ot * 32 + (lane & 31);
  int kb = 32 * c + (lane >> 5) * 16;
  int wd[4] = {0, 0, 0, 0};
#pragma unroll
  for (int e = 0; e < 16; e++) {
    float wv = (o < 410) ? wf1[(size_t)o * 1568 + kb + e] : 0.0f;
    long long m = llrint((double)wv * SC39);
    int d = 0;
    for (int jj = 0; jj <= j; jj++) {
      d = (int)((m + 128) & 255) - 128;
      m = (m - d) >> 8;
    }
    wd[e >> 2] |= (d & 255) << ((e & 3) * 8);
  }
  i32x4 v;
  v[0] = wd[0]; v[1] = wd[1]; v[2] = wd[2]; v[3] = wd[3];
  *(i32x4*)(BP + (size_t)i * 16) = v;
}

// Stage 5a: dense1 as exact i8-limb MFMA GEMM.  (unchanged)
__global__ __launch_bounds__(256) void k_dense1m(const unsigned char* __restrict__ s4,
                                                 const signed char* __restrict__ BP,
                                                 double* __restrict__ d5) {
  int ot = blockIdx.y;
  int w = threadIdx.x >> 6, l = threadIdx.x & 63;
  int col = l & 31, kh = l >> 5;
  int btTile = blockIdx.x * 4 + w;
  const unsigned char* arow = s4 + (size_t)(btTile * 32 + col) * 1568 + kh * 16;
  const i32x4* bpv = (const i32x4*)BP + (size_t)ot * 245 * 64 + l;
  i32x16 acc0, acc1, acc2, acc3, acc4;
#pragma unroll
  for (int r = 0; r < 16; r++) {
    acc0[r] = 0; acc1[r] = 0; acc2[r] = 0; acc3[r] = 0; acc4[r] = 0;
  }
  for (int c = 0; c < 49; c++) {
    i32x4 a = *(const i32x4*)(arow + 32 * c);
    i32x4 b0 = bpv[(0 * 49 + c) * 64];
    i32x4 b1 = bpv[(1 * 49 + c) * 64];
    i32x4 b2 = bpv[(2 * 49 + c) * 64];
    i32x4 b3 = bpv[(3 * 49 + c) * 64];
    i32x4 b4 = bpv[(4 * 49 + c) * 64];
    acc0 = __builtin_amdgcn_mfma_i32_32x32x32_i8(a, b0, acc0, 0, 0, 0);
    acc1 = __builtin_amdgcn_mfma_i32_32x32x32_i8(a, b1, acc1, 0, 0, 0);
    acc2 = __builtin_amdgcn_mfma_i32_32x32x32_i8(a, b2, acc2, 0, 0, 0);
    acc3 = __builtin_amdgcn_mfma_i32_32x32x32_i8(a, b3, acc3, 0, 0, 0);
    acc4 = __builtin_amdgcn_mfma_i32_32x32x32_i8(a, b4, acc4, 0, 0, 0);
  }
  int o = ot * 32 + col;
  if (o < 410) {
#pragma unroll
    for (int r = 0; r < 16; r++) {
      int R = (r & 3) + 8 * (r >> 2) + 4 * kh;
      double v = ((((double)acc4[r] * 256.0 + (double)acc3[r]) * 256.0 +
                   (double)acc2[r]) * 256.0 + (double)acc1[r]) * 256.0 + (double)acc0[r];
      d5[(size_t)(btTile * 32 + R) * 410 + o] = v * INV39;
    }
  }
}

// Stage 5b: psp + spike over dense1 output.  One thread per (b,o).
__global__ void k_psp5(const double* __restrict__ d5, unsigned char* __restrict__ s5) {
  int tid = blockIdx.x * 256 + threadIdx.x;
  if (tid >= B * 410) return;
  int o = tid % 410, b = tid / 410;
  double g1 = 0.0, g2 = 0.0;
  for (int t = 0; t < T; t++) {
    double s = d5[(size_t)(b * T + t) * 410 + o];
    g1 = s + A1 * g1;
    g2 = g1 + A1 * g2;
    s5[(size_t)(b * T + t) * 410 + o] = (CE * (g2 - g1) >= 1.0) ? 1 : 0;
  }
}

// Stage 6a: dense2 matmul.  One thread per (bt,o).
__global__ void k_dense2(const unsigned char* __restrict__ s5, const float* __restrict__ wf2,
                         double* __restrict__ d6) {
  int tid = blockIdx.x * 256 + threadIdx.x;
  if (tid >= B * T * 10) return;
  int o = tid % 10, bt = tid / 10;
  const unsigned char* sr = s5 + (size_t)bt * 410;
  const float* wr = wf2 + o * 410;
  double s = 0.0;
  for (int i = 0; i < 410; i++) s += (double)wr[i] * (double)sr[i];
  d6[tid] = s;
}

// Stage 6b: final psp + spike -> d_out [b][o][t] f32.
__global__ void k_psp6(const double* __restrict__ d6, float* __restrict__ out) {
  int tid = blockIdx.x * 256 + threadIdx.x;
  if (tid >= B * 10) return;
  int o = tid % 10, b = tid / 10;
  double g1 = 0.0, g2 = 0.0;
  for (int t = 0; t < T; t++) {
    double s = d6[(size_t)(b * T + t) * 10 + o];
    g1 = s + A1 * g1;
    g2 = g1 + A1 * g2;
    out[(size_t)b * 1000 + o * 100 + t] = (CE * (g2 - g1) >= 1.0) ? 1.0f : 0.0f;
  }
}

extern "C" void kernel_launch(void* const* d_in, const int* in_sizes, int n_in,
                              void* d_out, int out_size, void* d_ws, size_t ws_size,
                              hipStream_t stream) {
  const float* img = (const float*)d_in[0];
  const float* ru = (const float*)d_in[1];
  const float* w1 = (const float*)d_in[2];
  const float* w2 = (const float*)d_in[3];
  const float* wf1 = (const float*)d_in[4];
  const float* wf2 = (const float*)d_in[5];

  unsigned char* ws = (unsigned char*)d_ws;
  unsigned int* m1 = (unsigned int*)(ws + OFF_M1);
  unsigned int* m2 = (unsigned int*)(ws + OFF_M2);
  unsigned char* s4 = ws + OFF_S4;
  double* d5 = (double*)(ws + OFF_D5);
  unsigned char* s5 = ws + OFF_S5;
  double* d6 = (double*)(ws + OFF_D6);
  signed char* AP = (signed char*)(ws + OFF_AP);  // aliases d5 (freed before dense1m)
  signed char* BP = (signed char*)(ws + OFF_BP);
  float* out = (float*)d_out;

  k_encode_pack<<<(B * 28 * T + 255) / 256, 256, 0, stream>>>(img, ru, m1);
  k_limbs<<<(32 * 80 * 8 + 255) / 256, 256, 0, stream>>>(w2, AP);
  k_limbs2<<<(13 * 5 * 49 * 64 + 255) / 256, 256, 0, stream>>>(wf1, BP);
  k_conv1<<<B * 16, 256, 0, stream>>>(m1, w1, m2);
  k_conv2t<<<B * 7, 256, 0, stream>>>(m2, AP, s4);
  k_dense1m<<<dim3(25, 13), 256, 0, stream>>>(s4, BP, d5);
  k_psp5<<<(B * 410 + 255) / 256, 256, 0, stream>>>(d5, s5);
  k_dense2<<<(B * T * 10 + 255) / 256, 256, 0, stream>>>(s5, wf2, d6);
  k_psp6<<<2, 256, 0, stream>>>(d6, out);
}

// Round 9
// 404.770 us; speedup vs baseline: 1.6927x; 1.0193x over previous
//
#include <hip/hip_runtime.h>

// ---------------------------------------------------------------------------
// SLAYER-style spiking CNN forward pass, MI355X.  Round 7 (third submit; two
// prior attempts failed on GPU acquisition timeout — never measured).
//
// psp (SRM alpha kernel) as double-exponential IIR cascade (exact):
//   g1[t] = x[t] + a*g1[t-1]; g2[t] = g1[t] + a*g2[t-1]; u = (e/tau)*(g2-g1)
//
// R7: k_conv2u = k_conv2t with the three exposed-latency fixes R6's counters
//   demanded (7230 cyc/group measured vs ~1300 of issue work):
//   (a) async-STAGE split: next-group mask loads ISSUED at top of group
//       (hidden under the 50-MFMA conv phase), LDS-written after conv.
//       R6 did load->write inline before the barrier = fully exposed.
//   (b) IIR+pool merged: thread (o,pp) owns spike cols {2pp,2pp+1,14+2pp,
//       15+2pp} (exact pool partition) -> 4 spike chains + pool chain in
//       one thread; spk buffer + second barrier eliminated.
//   (c) part[] double-buffered by group parity -> ONE barrier per group
//       (leaders write part[np]/maskW[p], laggards read part[p]/maskW[np]
//       — disjoint within a barrier interval).
//   Arithmetic order identical to R6 (bit-exact): same limb recombine, same
//   (kg0+kg1)*INV39 sum, same IIR/pool expressions.
//   All other kernels unchanged.
// ---------------------------------------------------------------------------

namespace {
constexpr int B = 32, T = 100;
constexpr double A1 = 0.90483741803595957;  // exp(-1/10)
constexpr double CE = 0.27182818284590452;  // e/10
constexpr double SC39 = 549755813888.0;     // 2^39
constexpr double INV39 = 1.0 / 549755813888.0;

// workspace byte offsets
constexpr size_t OFF_M1 = 0;                                  // u32 [B*T][28]
constexpr size_t OFF_M2 = OFF_M1 + (size_t)B * T * 28 * 4;    // u32 [B*T][16][14]
constexpr size_t OFF_S4 = OFF_M2 + (size_t)B * T * 224 * 4;   // u8  [B*T][1568]
constexpr size_t OFF_D5 = OFF_S4 + (size_t)B * T * 1568;      // f64 [B*T][410]
constexpr size_t OFF_S5 = OFF_D5 + (size_t)B * T * 410 * 8;   // u8  [B*T][410]
constexpr size_t OFF_D6 = OFF_S5 + (size_t)B * T * 410;       // f64 [B*T][10]
constexpr size_t OFF_BP = OFF_D6 + (size_t)B * T * 10 * 8;    // i8  [13][5][49][64][16]
// A_pack (conv2 limbs) aliases the d5 region: written by k_limbs, read by
// k_conv2u, both complete before k_dense1m writes d5 (stream-ordered).
constexpr size_t OFF_AP = OFF_D5;
}  // namespace

using i32x4 = __attribute__((ext_vector_type(4))) int;
using i32x16 = __attribute__((ext_vector_type(16))) int;

// Stage 0: rate encode + bit-pack rows.  Thread per (b,y,t); loops x.
__global__ void k_encode_pack(const float* __restrict__ img, const float* __restrict__ ru,
                              unsigned int* __restrict__ m1) {
  int i = blockIdx.x * 256 + threadIdx.x;
  if (i >= B * 28 * T) return;
  int t = i % T;
  int y = (i / T) % 28;
  int b = i / (T * 28);
  unsigned int m = 0;
  const float* rb = ru + ((size_t)b * 784 + y * 28) * T + t;
  const float* ib = img + b * 784 + y * 28;
  for (int x = 0; x < 28; x++) {
    m |= (rb[(size_t)x * T] < ib[x]) ? (1u << x) : 0u;
  }
  m1[((size_t)b * T + t) * 28 + y] = m;
}

// Stage 1 fused: conv1 (1->16,5x5,pad2) + psp + spike + pool2 + psp + spike.
// (unchanged)
__global__ __launch_bounds__(256) void k_conv1(const unsigned int* __restrict__ m1,
                                               const float* __restrict__ w1,
                                               unsigned int* __restrict__ m2) {
  __shared__ double lut[160];            // [dy][32]
  __shared__ unsigned int mrow[2][32];   // rows iy=-2..29 at idx iy+2; guards 0
  __shared__ unsigned char spk[784];
  __shared__ unsigned char spkP[2][196];
  int o = blockIdx.x % 16, b = blockIdx.x / 16;
  int tid = threadIdx.x;
  if (tid < 160) {
    int dy = tid / 32, f = tid % 32;
    double v = 0.0;
    const float* wb = w1 + o * 25 + dy * 5;
#pragma unroll
    for (int dx = 0; dx < 5; dx++)
      if ((f >> dx) & 1) v += (double)wb[dx];
    lut[tid] = v;
  }
  if (tid < 32) {
    mrow[0][tid] = 0;
    mrow[1][tid] = 0;
  }
  int y = tid / 7, xg = tid % 7;
  int py = tid / 14, px = tid % 14;
  bool act = tid < 196;
  double g1[4] = {0, 0, 0, 0}, g2[4] = {0, 0, 0, 0};
  double p1 = 0.0, p2 = 0.0;
  const unsigned int* m1b = m1 + (size_t)b * T * 28;
  if (tid < 28) mrow[0][tid + 2] = m1b[tid] << 2;
  __syncthreads();
  for (int t = 0; t < T; t++) {
    int cur = t & 1, nxt = cur ^ 1;
    bool dold = (tid < 28) && (t + 1 < T);
    unsigned int ldv = 0;
    if (dold) ldv = m1b[(t + 1) * 28 + tid] << 2;
    if (act) {
      double s0 = 0, s1 = 0, s2 = 0, s3 = 0;
      int xb = xg * 4;
      const unsigned int* mc = mrow[cur];
#pragma unroll
      for (int dy = 0; dy < 5; dy++) {
        unsigned int m = mc[y + dy];
        const double* ld = lut + dy * 32;
        s0 += ld[(m >> (xb + 0)) & 31];
        s1 += ld[(m >> (xb + 1)) & 31];
        s2 += ld[(m >> (xb + 2)) & 31];
        s3 += ld[(m >> (xb + 3)) & 31];
      }
      g1[0] = s0 + A1 * g1[0]; g2[0] = g1[0] + A1 * g2[0];
      g1[1] = s1 + A1 * g1[1]; g2[1] = g1[1] + A1 * g2[1];
      g1[2] = s2 + A1 * g1[2]; g2[2] = g1[2] + A1 * g2[2];
      g1[3] = s3 + A1 * g1[3]; g2[3] = g1[3] + A1 * g2[3];
      unsigned char* sp = spk + y * 28 + xb;
      sp[0] = (CE * (g2[0] - g1[0]) >= 1.0) ? 1 : 0;
      sp[1] = (CE * (g2[1] - g1[1]) >= 1.0) ? 1 : 0;
      sp[2] = (CE * (g2[2] - g1[2]) >= 1.0) ? 1 : 0;
      sp[3] = (CE * (g2[3] - g1[3]) >= 1.0) ? 1 : 0;
    }
    if (dold) mrow[nxt][tid + 2] = ldv;
    __syncthreads();
    if (act) {
      const unsigned char* r0 = spk + (2 * py) * 28 + 2 * px;
      int sum = (int)r0[0] + (int)r0[1] + (int)r0[28] + (int)r0[29];
      double s = 1.1 * (double)sum;
      p1 = s + A1 * p1;
      p2 = p1 + A1 * p2;
      spkP[cur][tid] = (CE * (p2 - p1) >= 1.0) ? 1 : 0;
    }
    if (tid < 14 && t > 0) {
      unsigned int m = 0;
      const unsigned char* rp = spkP[nxt] + tid * 14;
#pragma unroll
      for (int xx = 0; xx < 14; xx++) m |= ((unsigned int)rp[xx]) << xx;
      m2[((size_t)(b * T + (t - 1)) * 16 + o) * 14 + tid] = m;
    }
    __syncthreads();
  }
  if (tid < 14) {
    unsigned int m = 0;
    const unsigned char* rp = spkP[(T - 1) & 1] + tid * 14;
#pragma unroll
    for (int xx = 0; xx < 14; xx++) m |= ((unsigned int)rp[xx]) << xx;
    m2[((size_t)(b * T + (T - 1)) * 16 + o) * 14 + tid] = m;
  }
}

// conv2 weight limbs: 5 signed base-256 digits of round(w2*2^39), laid out as
// MFMA A-fragments.  k' = (g<<3)+dx with g = 4c + 2eh + kh; row o = lane&31.
// (unchanged — layout verified bit-exact)
__global__ void k_limbs(const float* __restrict__ w2, signed char* __restrict__ AP) {
  int i = blockIdx.x * 256 + threadIdx.x;
  if (i >= 32 * 80 * 8) return;
  int dx = i & 7;
  int g = (i >> 3) % 80;
  int o = i / 640;
  int c = g >> 2, r = g & 3, eh = r >> 1, kh = r & 1;
  int lane = kh * 32 + o, e = eh * 8 + dx;
  int ci = g / 5, dy = g % 5;
  float wv = (dx < 5) ? w2[((o * 16 + ci) * 5 + dy) * 5 + dx] : 0.0f;
  long long m = llrint((double)wv * SC39);
#pragma unroll
  for (int j = 0; j < 5; j++) {
    int d = (int)((m + 128) & 255) - 128;
    AP[(size_t)((j * 20 + c) * 64 + lane) * 16 + e] = (signed char)d;
    m = (m - d) >> 8;
  }
}

// Stage 3 fused via exact i8 MFMA: conv2 + psp + spike + pool2 + psp + spike.
// Block = (b, row-pair yp), 4 waves = 2 t x 2 K-halves.  Single barrier per
// 2-t group; async-staged masks; merged IIR+pool on the (o,pp) partition.
__global__ __launch_bounds__(256, 1) void k_conv2u(const unsigned int* __restrict__ m2,
                                                   const signed char* __restrict__ AP,
                                                   unsigned char* __restrict__ s4) {
  // mask words, permuted so each lane's 20 words are contiguous:
  //   pos(H,g) = H*80 + (g&1)*40 + 2*(g>>2) + ((g>>1)&1)   [g = 4c+2eh+kh]
  __shared__ unsigned int maskW[2][2][176];     // [buf][slab tp][pos], 160 used
  __shared__ double part[2][2][2][32][30];      // [pbuf][tp][kg][o][col], 61.4KB
  int yp = blockIdx.x % 7, b = blockIdx.x / 7;
  int y0 = yp * 2;
  int tid = threadIdx.x;
  int w = tid >> 6, l = tid & 63;
  int tp = w >> 1, kg = w & 1;
  int col = l & 31, kh = l >> 5;
  int x = col % 14;
  unsigned int wmask = (col < 28) ? 31u : 0u;
  int half = (col >= 14) ? 1 : 0;
  const unsigned int* m2b = m2 + (size_t)b * T * 224;

  // ---- A preload: limbs 0..4, chunks 10kg..10kg+9 (static over t) ----
  const i32x4* APv = (const i32x4*)AP;
  i32x4 Af[5][10];
#pragma unroll
  for (int j = 0; j < 5; j++)
#pragma unroll
    for (int cl = 0; cl < 10; cl++)
      Af[j][cl] = APv[(size_t)((j * 20) + kg * 10 + cl) * 64 + l];

  // ---- stage lane constants (waves 0,1): LDS pos + m2 index per pass ----
  int stPos[3] = {-1, -1, -1}, stIdx[3] = {-1, -1, -1};
  if (w < 2) {
#pragma unroll
    for (int pass = 0; pass < 3; pass++) {
      if (pass == 2 && l >= 32) continue;
      int e = pass * 64 + l;
      int H = e / 80, g = e % 80;
      int ci = g / 5, dy = g % 5;
      int iy = y0 - 2 + H + dy;
      stPos[pass] = H * 80 + (g & 1) * 40 + 2 * (g >> 2) + ((g >> 1) & 1);
      if (iy >= 0 && iy < 14) stIdx[pass] = ci * 14 + iy;
    }
  }

  // ---- merged IIR+pool mapping: thread (po, pp) owns spike cols
  //      {2pp, 2pp+1, 14+2pp, 15+2pp} and the pool chain ----
  int po = tid / 7, pp = tid % 7;
  bool chainAct = tid < 224;
  double sg1[4] = {0, 0, 0, 0}, sg2[4] = {0, 0, 0, 0};  // spike IIR per col
  double q1 = 0.0, q2 = 0.0;                            // pool IIR

  // ---- prologue: stage masks for t=0,1 into buf 0 ----
  if (w < 2) {
#pragma unroll
    for (int pass = 0; pass < 3; pass++) {
      if (stPos[pass] < 0) continue;
      unsigned int v = 0;
      if (stIdx[pass] >= 0) v = m2b[(size_t)w * 224 + stIdx[pass]] << 2;
      maskW[0][w][stPos[pass]] = v;
    }
  }
  __syncthreads();

  for (int grp = 0; grp < 50; grp++) {
    int p = grp & 1, np = p ^ 1;

    // (a) ISSUE next-group mask loads early — hidden under the conv phase
    unsigned int ld0 = 0, ld1 = 0, ld2 = 0;
    bool doStage = (w < 2) && (grp + 1 < 50);
    if (doStage) {
      size_t tb = (size_t)((grp + 1) * 2 + w) * 224;
      if (stIdx[0] >= 0) ld0 = m2b[tb + stIdx[0]] << 2;
      if (stIdx[1] >= 0) ld1 = m2b[tb + stIdx[1]] << 2;
      if (stIdx[2] >= 0) ld2 = m2b[tb + stIdx[2]] << 2;
    }

    // (b) conv: this wave's (t = grp*2+tp, K-half kg), all 5 limbs
    {
      const uint4* mwv = (const uint4*)&maskW[p][tp][0];
      int base4 = half * 20 + kh * 10 + 5 * kg;  // uint4 index of 20-word run
      uint4 mk0 = mwv[base4 + 0], mk1 = mwv[base4 + 1], mk2 = mwv[base4 + 2];
      uint4 mk3 = mwv[base4 + 3], mk4 = mwv[base4 + 4];
      i32x16 ac0, ac1, ac2, ac3, ac4;
#pragma unroll
      for (int r = 0; r < 16; r++) { ac0[r] = 0; ac1[r] = 0; ac2[r] = 0; ac3[r] = 0; ac4[r] = 0; }
#pragma unroll
      for (int cl = 0; cl < 10; cl++) {
        uint4 mkv = (cl < 2) ? mk0 : (cl < 4) ? mk1 : (cl < 6) ? mk2 : (cl < 8) ? mk3 : mk4;
        unsigned int ra = (cl & 1) ? mkv.z : mkv.x;
        unsigned int rb = (cl & 1) ? mkv.w : mkv.y;
        unsigned int a5 = (ra >> x) & wmask;
        unsigned int b5 = (rb >> x) & wmask;
        i32x4 bb;
        bb[0] = (int)(((a5 & 15u) * 0x204081u) & 0x01010101u);
        bb[1] = (int)((a5 >> 4) & 1u);
        bb[2] = (int)(((b5 & 15u) * 0x204081u) & 0x01010101u);
        bb[3] = (int)((b5 >> 4) & 1u);
        ac0 = __builtin_amdgcn_mfma_i32_32x32x32_i8(Af[0][cl], bb, ac0, 0, 0, 0);
        ac1 = __builtin_amdgcn_mfma_i32_32x32x32_i8(Af[1][cl], bb, ac1, 0, 0, 0);
        ac2 = __builtin_amdgcn_mfma_i32_32x32x32_i8(Af[2][cl], bb, ac2, 0, 0, 0);
        ac3 = __builtin_amdgcn_mfma_i32_32x32x32_i8(Af[3][cl], bb, ac3, 0, 0, 0);
        ac4 = __builtin_amdgcn_mfma_i32_32x32x32_i8(Af[4][cl], bb, ac4, 0, 0, 0);
      }
      // exact integer limb recombine -> f64 partial (|value| < 2^49, exact)
      if (col < 28) {
#pragma unroll
        for (int r = 0; r < 16; r++) {
          int R = (r & 3) + 8 * (r >> 2) + 4 * kh;
          int c01 = ac1[r] * 256 + ac0[r];
          int c23 = ac3[r] * 256 + ac2[r];
          double S = ((double)ac4[r] * 65536.0 + (double)c23) * 65536.0 + (double)c01;
          part[p][tp][kg][R][col] = S;
        }
      }
    }

    // (a') LATE LDS-write of the staged masks (loads have had ~conv to land)
    if (doStage) {
      if (stPos[0] >= 0) maskW[np][w][stPos[0]] = ld0;
      if (stPos[1] >= 0) maskW[np][w][stPos[1]] = ld1;
      if (stPos[2] >= 0) maskW[np][w][stPos[2]] = ld2;
    }
    __syncthreads();  // single barrier: part[p] complete + maskW[np] staged

    // (c) merged IIR + pool: read part[p], 2 timesteps in order
    if (chainAct) {
#pragma unroll
      for (int g = 0; g < 2; g++) {
        const double* a0 = &part[p][g][0][po][2 * pp];        // cols 2pp,2pp+1 (kg0)
        const double* b0 = &part[p][g][1][po][2 * pp];        // (kg1)
        const double* a1 = &part[p][g][0][po][14 + 2 * pp];   // cols 14+2pp,15+2pp
        const double* b1 = &part[p][g][1][po][14 + 2 * pp];
        double c0 = (a0[0] + b0[0]) * INV39;
        double c1 = (a0[1] + b0[1]) * INV39;
        double c2 = (a1[0] + b1[0]) * INV39;
        double c3 = (a1[1] + b1[1]) * INV39;
        sg1[0] = c0 + A1 * sg1[0]; sg2[0] = sg1[0] + A1 * sg2[0];
        sg1[1] = c1 + A1 * sg1[1]; sg2[1] = sg1[1] + A1 * sg2[1];
        sg1[2] = c2 + A1 * sg1[2]; sg2[2] = sg1[2] + A1 * sg2[2];
        sg1[3] = c3 + A1 * sg1[3]; sg2[3] = sg1[3] + A1 * sg2[3];
        int sum = ((CE * (sg2[0] - sg1[0]) >= 1.0) ? 1 : 0)
                + ((CE * (sg2[1] - sg1[1]) >= 1.0) ? 1 : 0)
                + ((CE * (sg2[2] - sg1[2]) >= 1.0) ? 1 : 0)
                + ((CE * (sg2[3] - sg1[3]) >= 1.0) ? 1 : 0);
        double s = 1.1 * (double)sum;
        q1 = s + A1 * q1;
        q2 = q1 + A1 * q2;
        s4[(size_t)(b * T + grp * 2 + g) * 1568 + po * 49 + yp * 7 + pp] =
            (CE * (q2 - q1) >= 1.0) ? 1 : 0;
      }
    }
    // no second barrier: next group's conv writes part[np]/reads maskW[np];
    // laggards here read part[p] — disjoint within one barrier interval.
  }
}

// dense1 weight limbs: 5 signed base-256 digits of round(wf1*2^39), packed as
// MFMA B-fragments with logical k = kh*16 + e.  (unchanged)
__global__ void k_limbs2(const float* __restrict__ wf1, signed char* __restrict__ BP) {
  int i = blockIdx.x * 256 + threadIdx.x;
  if (i >= 13 * 5 * 49 * 64) return;
  int lane = i & 63;
  int fi = i >> 6;
  int c = fi % 49;
  int j = (fi / 49) % 5;
  int ot = fi / 245;
  int o = ot * 32 + (lane & 31);
  int kb = 32 * c + (lane >> 5) * 16;
  int wd[4] = {0, 0, 0, 0};
#pragma unroll
  for (int e = 0; e < 16; e++) {
    float wv = (o < 410) ? wf1[(size_t)o * 1568 + kb + e] : 0.0f;
    long long m = llrint((double)wv * SC39);
    int d = 0;
    for (int jj = 0; jj <= j; jj++) {
      d = (int)((m + 128) & 255) - 128;
      m = (m - d) >> 8;
    }
    wd[e >> 2] |= (d & 255) << ((e & 3) * 8);
  }
  i32x4 v;
  v[0] = wd[0]; v[1] = wd[1]; v[2] = wd[2]; v[3] = wd[3];
  *(i32x4*)(BP + (size_t)i * 16) = v;
}

// Stage 5a: dense1 as exact i8-limb MFMA GEMM.  (unchanged)
__global__ __launch_bounds__(256) void k_dense1m(const unsigned char* __restrict__ s4,
                                                 const signed char* __restrict__ BP,
                                                 double* __restrict__ d5) {
  int ot = blockIdx.y;
  int w = threadIdx.x >> 6, l = threadIdx.x & 63;
  int col = l & 31, kh = l >> 5;
  int btTile = blockIdx.x * 4 + w;
  const unsigned char* arow = s4 + (size_t)(btTile * 32 + col) * 1568 + kh * 16;
  const i32x4* bpv = (const i32x4*)BP + (size_t)ot * 245 * 64 + l;
  i32x16 acc0, acc1, acc2, acc3, acc4;
#pragma unroll
  for (int r = 0; r < 16; r++) {
    acc0[r] = 0; acc1[r] = 0; acc2[r] = 0; acc3[r] = 0; acc4[r] = 0;
  }
  for (int c = 0; c < 49; c++) {
    i32x4 a = *(const i32x4*)(arow + 32 * c);
    i32x4 b0 = bpv[(0 * 49 + c) * 64];
    i32x4 b1 = bpv[(1 * 49 + c) * 64];
    i32x4 b2 = bpv[(2 * 49 + c) * 64];
    i32x4 b3 = bpv[(3 * 49 + c) * 64];
    i32x4 b4 = bpv[(4 * 49 + c) * 64];
    acc0 = __builtin_amdgcn_mfma_i32_32x32x32_i8(a, b0, acc0, 0, 0, 0);
    acc1 = __builtin_amdgcn_mfma_i32_32x32x32_i8(a, b1, acc1, 0, 0, 0);
    acc2 = __builtin_amdgcn_mfma_i32_32x32x32_i8(a, b2, acc2, 0, 0, 0);
    acc3 = __builtin_amdgcn_mfma_i32_32x32x32_i8(a, b3, acc3, 0, 0, 0);
    acc4 = __builtin_amdgcn_mfma_i32_32x32x32_i8(a, b4, acc4, 0, 0, 0);
  }
  int o = ot * 32 + col;
  if (o < 410) {
#pragma unroll
    for (int r = 0; r < 16; r++) {
      int R = (r & 3) + 8 * (r >> 2) + 4 * kh;
      double v = ((((double)acc4[r] * 256.0 + (double)acc3[r]) * 256.0 +
                   (double)acc2[r]) * 256.0 + (double)acc1[r]) * 256.0 + (double)acc0[r];
      d5[(size_t)(btTile * 32 + R) * 410 + o] = v * INV39;
    }
  }
}

// Stage 5b: psp + spike over dense1 output.  One thread per (b,o).
__global__ void k_psp5(const double* __restrict__ d5, unsigned char* __restrict__ s5) {
  int tid = blockIdx.x * 256 + threadIdx.x;
  if (tid >= B * 410) return;
  int o = tid % 410, b = tid / 410;
  double g1 = 0.0, g2 = 0.0;
  for (int t = 0; t < T; t++) {
    double s = d5[(size_t)(b * T + t) * 410 + o];
    g1 = s + A1 * g1;
    g2 = g1 + A1 * g2;
    s5[(size_t)(b * T + t) * 410 + o] = (CE * (g2 - g1) >= 1.0) ? 1 : 0;
  }
}

// Stage 6a: dense2 matmul.  One thread per (bt,o).
__global__ void k_dense2(const unsigned char* __restrict__ s5, const float* __restrict__ wf2,
                         double* __restrict__ d6) {
  int tid = blockIdx.x * 256 + threadIdx.x;
  if (tid >= B * T * 10) return;
  int o = tid % 10, bt = tid / 10;
  const unsigned char* sr = s5 + (size_t)bt * 410;
  const float* wr = wf2 + o * 410;
  double s = 0.0;
  for (int i = 0; i < 410; i++) s += (double)wr[i] * (double)sr[i];
  d6[tid] = s;
}

// Stage 6b: final psp + spike -> d_out [b][o][t] f32.
__global__ void k_psp6(const double* __restrict__ d6, float* __restrict__ out) {
  int tid = blockIdx.x * 256 + threadIdx.x;
  if (tid >= B * 10) return;
  int o = tid % 10, b = tid / 10;
  double g1 = 0.0, g2 = 0.0;
  for (int t = 0; t < T; t++) {
    double s = d6[(size_t)(b * T + t) * 10 + o];
    g1 = s + A1 * g1;
    g2 = g1 + A1 * g2;
    out[(size_t)b * 1000 + o * 100 + t] = (CE * (g2 - g1) >= 1.0) ? 1.0f : 0.0f;
  }
}

extern "C" void kernel_launch(void* const* d_in, const int* in_sizes, int n_in,
                              void* d_out, int out_size, void* d_ws, size_t ws_size,
                              hipStream_t stream) {
  const float* img = (const float*)d_in[0];
  const float* ru = (const float*)d_in[1];
  const float* w1 = (const float*)d_in[2];
  const float* w2 = (const float*)d_in[3];
  const float* wf1 = (const float*)d_in[4];
  const float* wf2 = (const float*)d_in[5];

  unsigned char* ws = (unsigned char*)d_ws;
  unsigned int* m1 = (unsigned int*)(ws + OFF_M1);
  unsigned int* m2 = (unsigned int*)(ws + OFF_M2);
  unsigned char* s4 = ws + OFF_S4;
  double* d5 = (double*)(ws + OFF_D5);
  unsigned char* s5 = ws + OFF_S5;
  double* d6 = (double*)(ws + OFF_D6);
  signed char* AP = (signed char*)(ws + OFF_AP);  // aliases d5 (freed before dense1m)
  signed char* BP = (signed char*)(ws + OFF_BP);
  float* out = (float*)d_out;

  k_encode_pack<<<(B * 28 * T + 255) / 256, 256, 0, stream>>>(img, ru, m1);
  k_limbs<<<(32 * 80 * 8 + 255) / 256, 256, 0, stream>>>(w2, AP);
  k_limbs2<<<(13 * 5 * 49 * 64 + 255) / 256, 256, 0, stream>>>(wf1, BP);
  k_conv1<<<B * 16, 256, 0, stream>>>(m1, w1, m2);
  k_conv2u<<<B * 7, 256, 0, stream>>>(m2, AP, s4);
  k_dense1m<<<dim3(25, 13), 256, 0, stream>>>(s4, BP, d5);
  k_psp5<<<(B * 410 + 255) / 256, 256, 0, stream>>>(d5, s5);
  k_dense2<<<(B * T * 10 + 255) / 256, 256, 0, stream>>>(s5, wf2, d6);
  k_psp6<<<2, 256, 0, stream>>>(d6, out);
}

// Round 10
// 375.975 us; speedup vs baseline: 1.8224x; 1.0766x over previous
//
#include <hip/hip_runtime.h>

// ---------------------------------------------------------------------------
// SLAYER-style spiking CNN forward pass, MI355X.  Round 8.
//
// psp (SRM alpha kernel) as double-exponential IIR cascade (exact):
//   g1[t] = x[t] + a*g1[t-1]; g2[t] = g1[t] + a*g2[t-1]; u = (e/tau)*(g2-g1)
//
// R8: k_conv2w = conv2 at 2 waves/SIMD.  R7 measured 6800 cyc/group with
//   MfmaUtil 20% + VALUBusy 29%: at 1 wave/SIMD the wave's MFMA (50x32 cyc
//   per SIMD) and VALU (~2000 cyc) serialize — one wave never co-issues.
//   New shape: 512 threads = 8 waves = (2 timesteps x 4 K-QUARTERS); per-wave
//   A-preload 25 frags (100 VGPR) + 80 acc fits 2 waves/SIMD
//   (launch_bounds(512,2)).  Each SIMD gets one conv(+stage) wave + one
//   conv(+IIR) wave -> MFMA and VALU overlap across waves (m114).
//   part single-buffered [tp][kq][32][30] (61.4 KB; LDS total 64.5 KB),
//   2 barriers/group.  kq-sum in IIR: all partials exact ints < 2^47 ->
//   bit-exact regardless of order.  Masks re-permuted into 12-word padded
//   kq runs (16B-aligned uint4 reads).  All other kernels unchanged.
// ---------------------------------------------------------------------------

namespace {
constexpr int B = 32, T = 100;
constexpr double A1 = 0.90483741803595957;  // exp(-1/10)
constexpr double CE = 0.27182818284590452;  // e/10
constexpr double SC39 = 549755813888.0;     // 2^39
constexpr double INV39 = 1.0 / 549755813888.0;

// workspace byte offsets
constexpr size_t OFF_M1 = 0;                                  // u32 [B*T][28]
constexpr size_t OFF_M2 = OFF_M1 + (size_t)B * T * 28 * 4;    // u32 [B*T][16][14]
constexpr size_t OFF_S4 = OFF_M2 + (size_t)B * T * 224 * 4;   // u8  [B*T][1568]
constexpr size_t OFF_D5 = OFF_S4 + (size_t)B * T * 1568;      // f64 [B*T][410]
constexpr size_t OFF_S5 = OFF_D5 + (size_t)B * T * 410 * 8;   // u8  [B*T][410]
constexpr size_t OFF_D6 = OFF_S5 + (size_t)B * T * 410;       // f64 [B*T][10]
constexpr size_t OFF_BP = OFF_D6 + (size_t)B * T * 10 * 8;    // i8  [13][5][49][64][16]
// A_pack (conv2 limbs) aliases the d5 region: written by k_limbs, read by
// k_conv2w, both complete before k_dense1m writes d5 (stream-ordered).
constexpr size_t OFF_AP = OFF_D5;
}  // namespace

using i32x4 = __attribute__((ext_vector_type(4))) int;
using i32x16 = __attribute__((ext_vector_type(16))) int;

// Stage 0: rate encode + bit-pack rows.  Thread per (b,y,t); loops x.
__global__ void k_encode_pack(const float* __restrict__ img, const float* __restrict__ ru,
                              unsigned int* __restrict__ m1) {
  int i = blockIdx.x * 256 + threadIdx.x;
  if (i >= B * 28 * T) return;
  int t = i % T;
  int y = (i / T) % 28;
  int b = i / (T * 28);
  unsigned int m = 0;
  const float* rb = ru + ((size_t)b * 784 + y * 28) * T + t;
  const float* ib = img + b * 784 + y * 28;
  for (int x = 0; x < 28; x++) {
    m |= (rb[(size_t)x * T] < ib[x]) ? (1u << x) : 0u;
  }
  m1[((size_t)b * T + t) * 28 + y] = m;
}

// Stage 1 fused: conv1 (1->16,5x5,pad2) + psp + spike + pool2 + psp + spike.
// (unchanged)
__global__ __launch_bounds__(256) void k_conv1(const unsigned int* __restrict__ m1,
                                               const float* __restrict__ w1,
                                               unsigned int* __restrict__ m2) {
  __shared__ double lut[160];            // [dy][32]
  __shared__ unsigned int mrow[2][32];   // rows iy=-2..29 at idx iy+2; guards 0
  __shared__ unsigned char spk[784];
  __shared__ unsigned char spkP[2][196];
  int o = blockIdx.x % 16, b = blockIdx.x / 16;
  int tid = threadIdx.x;
  if (tid < 160) {
    int dy = tid / 32, f = tid % 32;
    double v = 0.0;
    const float* wb = w1 + o * 25 + dy * 5;
#pragma unroll
    for (int dx = 0; dx < 5; dx++)
      if ((f >> dx) & 1) v += (double)wb[dx];
    lut[tid] = v;
  }
  if (tid < 32) {
    mrow[0][tid] = 0;
    mrow[1][tid] = 0;
  }
  int y = tid / 7, xg = tid % 7;
  int py = tid / 14, px = tid % 14;
  bool act = tid < 196;
  double g1[4] = {0, 0, 0, 0}, g2[4] = {0, 0, 0, 0};
  double p1 = 0.0, p2 = 0.0;
  const unsigned int* m1b = m1 + (size_t)b * T * 28;
  if (tid < 28) mrow[0][tid + 2] = m1b[tid] << 2;
  __syncthreads();
  for (int t = 0; t < T; t++) {
    int cur = t & 1, nxt = cur ^ 1;
    bool dold = (tid < 28) && (t + 1 < T);
    unsigned int ldv = 0;
    if (dold) ldv = m1b[(t + 1) * 28 + tid] << 2;
    if (act) {
      double s0 = 0, s1 = 0, s2 = 0, s3 = 0;
      int xb = xg * 4;
      const unsigned int* mc = mrow[cur];
#pragma unroll
      for (int dy = 0; dy < 5; dy++) {
        unsigned int m = mc[y + dy];
        const double* ld = lut + dy * 32;
        s0 += ld[(m >> (xb + 0)) & 31];
        s1 += ld[(m >> (xb + 1)) & 31];
        s2 += ld[(m >> (xb + 2)) & 31];
        s3 += ld[(m >> (xb + 3)) & 31];
      }
      g1[0] = s0 + A1 * g1[0]; g2[0] = g1[0] + A1 * g2[0];
      g1[1] = s1 + A1 * g1[1]; g2[1] = g1[1] + A1 * g2[1];
      g1[2] = s2 + A1 * g1[2]; g2[2] = g1[2] + A1 * g2[2];
      g1[3] = s3 + A1 * g1[3]; g2[3] = g1[3] + A1 * g2[3];
      unsigned char* sp = spk + y * 28 + xb;
      sp[0] = (CE * (g2[0] - g1[0]) >= 1.0) ? 1 : 0;
      sp[1] = (CE * (g2[1] - g1[1]) >= 1.0) ? 1 : 0;
      sp[2] = (CE * (g2[2] - g1[2]) >= 1.0) ? 1 : 0;
      sp[3] = (CE * (g2[3] - g1[3]) >= 1.0) ? 1 : 0;
    }
    if (dold) mrow[nxt][tid + 2] = ldv;
    __syncthreads();
    if (act) {
      const unsigned char* r0 = spk + (2 * py) * 28 + 2 * px;
      int sum = (int)r0[0] + (int)r0[1] + (int)r0[28] + (int)r0[29];
      double s = 1.1 * (double)sum;
      p1 = s + A1 * p1;
      p2 = p1 + A1 * p2;
      spkP[cur][tid] = (CE * (p2 - p1) >= 1.0) ? 1 : 0;
    }
    if (tid < 14 && t > 0) {
      unsigned int m = 0;
      const unsigned char* rp = spkP[nxt] + tid * 14;
#pragma unroll
      for (int xx = 0; xx < 14; xx++) m |= ((unsigned int)rp[xx]) << xx;
      m2[((size_t)(b * T + (t - 1)) * 16 + o) * 14 + tid] = m;
    }
    __syncthreads();
  }
  if (tid < 14) {
    unsigned int m = 0;
    const unsigned char* rp = spkP[(T - 1) & 1] + tid * 14;
#pragma unroll
    for (int xx = 0; xx < 14; xx++) m |= ((unsigned int)rp[xx]) << xx;
    m2[((size_t)(b * T + (T - 1)) * 16 + o) * 14 + tid] = m;
  }
}

// conv2 weight limbs: 5 signed base-256 digits of round(w2*2^39), laid out as
// MFMA A-fragments.  k' = (g<<3)+dx with g = 4c + 2eh + kh; row o = lane&31.
// (unchanged — layout verified bit-exact)
__global__ void k_limbs(const float* __restrict__ w2, signed char* __restrict__ AP) {
  int i = blockIdx.x * 256 + threadIdx.x;
  if (i >= 32 * 80 * 8) return;
  int dx = i & 7;
  int g = (i >> 3) % 80;
  int o = i / 640;
  int c = g >> 2, r = g & 3, eh = r >> 1, kh = r & 1;
  int lane = kh * 32 + o, e = eh * 8 + dx;
  int ci = g / 5, dy = g % 5;
  float wv = (dx < 5) ? w2[((o * 16 + ci) * 5 + dy) * 5 + dx] : 0.0f;
  long long m = llrint((double)wv * SC39);
#pragma unroll
  for (int j = 0; j < 5; j++) {
    int d = (int)((m + 128) & 255) - 128;
    AP[(size_t)((j * 20 + c) * 64 + lane) * 16 + e] = (signed char)d;
    m = (m - d) >> 8;
  }
}

// Stage 3 fused via exact i8 MFMA: conv2 + psp + spike + pool2 + psp + spike.
// Block = (b, row-pair yp), 512 threads = 8 waves = 2 timesteps x 4 K-quarters.
// 2 waves/SIMD -> MFMA of one wave overlaps VALU of the other.
// Masks permuted into 12-word-padded (H,kh,kq) runs (16B-aligned uint4 reads):
//   pos(H,g) = H*96 + kh*48 + kq*12 + q*2 + eh   [g=4c+2eh+kh, kq=c/5, q=c%5]
__global__ __launch_bounds__(512, 2) void k_conv2w(const unsigned int* __restrict__ m2,
                                                   const signed char* __restrict__ AP,
                                                   unsigned char* __restrict__ s4) {
  __shared__ unsigned int maskW[2][2][192];  // [buf][slab tp][pos]; 3072 B
  __shared__ double part[2][4][32][30];      // [tp][kq][R][col]; 61440 B
  int yp = blockIdx.x % 7, b = blockIdx.x / 7;
  int y0 = yp * 2;
  int tid = threadIdx.x;
  int w = tid >> 6, l = tid & 63;
  int tp = w & 1, kq = w >> 1;
  int col = l & 31, kh = l >> 5;
  int x = col % 14;
  unsigned int wmask = (col < 28) ? 31u : 0u;
  int half = (col >= 14) ? 1 : 0;
  const unsigned int* m2b = m2 + (size_t)b * T * 224;

  // ---- A preload: 5 limbs x 5 chunks (global chunk 5kq+q) = 25 frags ----
  const i32x4* APv = (const i32x4*)AP;
  i32x4 Af[5][5];
#pragma unroll
  for (int j = 0; j < 5; j++)
#pragma unroll
    for (int q = 0; q < 5; q++)
      Af[j][q] = APv[(size_t)(j * 20 + 5 * kq + q) * 64 + l];

  // ---- stager constants (waves 0,1 = slabs tp 0,1): 3 passes over 160 ----
  int stPos[3] = {-1, -1, -1}, stIdx[3] = {-1, -1, -1};
  if (w < 2) {
#pragma unroll
    for (int pass = 0; pass < 3; pass++) {
      if (pass == 2 && l >= 32) continue;
      int e = pass * 64 + l;
      int H = e / 80, g = e % 80;
      int c = g >> 2, eh2 = (g >> 1) & 1, kh2 = g & 1;
      int kq2 = c / 5, q2 = c % 5;
      int ci = g / 5, dy = g % 5;
      int iy = y0 - 2 + H + dy;
      stPos[pass] = H * 96 + kh2 * 48 + kq2 * 12 + q2 * 2 + eh2;
      if (iy >= 0 && iy < 14) stIdx[pass] = ci * 14 + iy;
    }
  }

  // ---- chain mapping: waves 4-7 -> ct in [0,224): (po, pp) ----
  int ct = tid - 256;
  bool chainAct = (ct >= 0) && (ct < 224);
  int po = (ct >= 0) ? ct / 7 : 0;
  int pp = (ct >= 0) ? ct % 7 : 0;
  double sg1[4] = {0, 0, 0, 0}, sg2[4] = {0, 0, 0, 0};  // spike IIR per col
  double pq1 = 0.0, pq2 = 0.0;                          // pool IIR

  // ---- prologue: stage masks for t=0 (slab 0) and t=1 (slab 1) ----
  if (w < 2) {
#pragma unroll
    for (int pass = 0; pass < 3; pass++) {
      if (stPos[pass] < 0) continue;
      unsigned int v = 0;
      if (stIdx[pass] >= 0) v = m2b[(size_t)w * 224 + stIdx[pass]] << 2;
      maskW[0][w][stPos[pass]] = v;
    }
  }
  __syncthreads();

  for (int grp = 0; grp < 50; grp++) {
    int p = grp & 1, np = p ^ 1;

    // issue next-group mask loads early (hidden under conv)
    unsigned int ld0 = 0, ld1 = 0, ld2 = 0;
    bool doStage = (w < 2) && (grp + 1 < 50);
    if (doStage) {
      size_t tb = (size_t)((grp + 1) * 2 + w) * 224;
      if (stIdx[0] >= 0) ld0 = m2b[tb + stIdx[0]] << 2;
      if (stIdx[1] >= 0) ld1 = m2b[tb + stIdx[1]] << 2;
      if (stIdx[2] >= 0) ld2 = m2b[tb + stIdx[2]] << 2;
    }

    // conv: this wave's (t = grp*2+tp, K-quarter kq), all 5 limbs
    {
      const uint4* mwv = (const uint4*)&maskW[p][tp][0];
      int base4 = half * 24 + kh * 12 + kq * 3;
      uint4 mk0 = mwv[base4 + 0], mk1 = mwv[base4 + 1], mk2 = mwv[base4 + 2];
      i32x16 ac0, ac1, ac2, ac3, ac4;
#pragma unroll
      for (int r = 0; r < 16; r++) { ac0[r] = 0; ac1[r] = 0; ac2[r] = 0; ac3[r] = 0; ac4[r] = 0; }
#pragma unroll
      for (int q = 0; q < 5; q++) {
        unsigned int ra = (q == 0) ? mk0.x : (q == 1) ? mk0.z : (q == 2) ? mk1.x
                         : (q == 3) ? mk1.z : mk2.x;
        unsigned int rb = (q == 0) ? mk0.y : (q == 1) ? mk0.w : (q == 2) ? mk1.y
                         : (q == 3) ? mk1.w : mk2.y;
        unsigned int a5 = (ra >> x) & wmask;
        unsigned int b5 = (rb >> x) & wmask;
        i32x4 bb;
        bb[0] = (int)(((a5 & 15u) * 0x204081u) & 0x01010101u);
        bb[1] = (int)((a5 >> 4) & 1u);
        bb[2] = (int)(((b5 & 15u) * 0x204081u) & 0x01010101u);
        bb[3] = (int)((b5 >> 4) & 1u);
        ac0 = __builtin_amdgcn_mfma_i32_32x32x32_i8(Af[0][q], bb, ac0, 0, 0, 0);
        ac1 = __builtin_amdgcn_mfma_i32_32x32x32_i8(Af[1][q], bb, ac1, 0, 0, 0);
        ac2 = __builtin_amdgcn_mfma_i32_32x32x32_i8(Af[2][q], bb, ac2, 0, 0, 0);
        ac3 = __builtin_amdgcn_mfma_i32_32x32x32_i8(Af[3][q], bb, ac3, 0, 0, 0);
        ac4 = __builtin_amdgcn_mfma_i32_32x32x32_i8(Af[4][q], bb, ac4, 0, 0, 0);
      }
      // exact integer limb recombine -> f64 partial (|value| < 2^47, exact)
      if (col < 28) {
#pragma unroll
        for (int r = 0; r < 16; r++) {
          int R = (r & 3) + 8 * (r >> 2) + 4 * kh;
          int c01 = ac1[r] * 256 + ac0[r];
          int c23 = ac3[r] * 256 + ac2[r];
          double S = ((double)ac4[r] * 65536.0 + (double)c23) * 65536.0 + (double)c01;
          part[tp][kq][R][col] = S;
        }
      }
    }

    // late LDS-write of staged masks (loads hidden under conv)
    if (doStage) {
      if (stPos[0] >= 0) maskW[np][w][stPos[0]] = ld0;
      if (stPos[1] >= 0) maskW[np][w][stPos[1]] = ld1;
      if (stPos[2] >= 0) maskW[np][w][stPos[2]] = ld2;
    }
    __syncthreads();  // B1: part complete + next masks staged

    // merged IIR + pool (waves 4-7): 2 timesteps in order; kq-sum exact
    if (chainAct) {
#pragma unroll
      for (int g = 0; g < 2; g++) {
        const double* q0a = &part[g][0][po][2 * pp];
        const double* q1a = &part[g][1][po][2 * pp];
        const double* q2a = &part[g][2][po][2 * pp];
        const double* q3a = &part[g][3][po][2 * pp];
        const double* q0b = &part[g][0][po][14 + 2 * pp];
        const double* q1b = &part[g][1][po][14 + 2 * pp];
        const double* q2b = &part[g][2][po][14 + 2 * pp];
        const double* q3b = &part[g][3][po][14 + 2 * pp];
        double c0 = ((q0a[0] + q1a[0]) + (q2a[0] + q3a[0])) * INV39;
        double c1 = ((q0a[1] + q1a[1]) + (q2a[1] + q3a[1])) * INV39;
        double c2 = ((q0b[0] + q1b[0]) + (q2b[0] + q3b[0])) * INV39;
        double c3 = ((q0b[1] + q1b[1]) + (q2b[1] + q3b[1])) * INV39;
        sg1[0] = c0 + A1 * sg1[0]; sg2[0] = sg1[0] + A1 * sg2[0];
        sg1[1] = c1 + A1 * sg1[1]; sg2[1] = sg1[1] + A1 * sg2[1];
        sg1[2] = c2 + A1 * sg1[2]; sg2[2] = sg1[2] + A1 * sg2[2];
        sg1[3] = c3 + A1 * sg1[3]; sg2[3] = sg1[3] + A1 * sg2[3];
        int sum = ((CE * (sg2[0] - sg1[0]) >= 1.0) ? 1 : 0)
                + ((CE * (sg2[1] - sg1[1]) >= 1.0) ? 1 : 0)
                + ((CE * (sg2[2] - sg1[2]) >= 1.0) ? 1 : 0)
                + ((CE * (sg2[3] - sg1[3]) >= 1.0) ? 1 : 0);
        double s = 1.1 * (double)sum;
        pq1 = s + A1 * pq1;
        pq2 = pq1 + A1 * pq2;
        s4[(size_t)(b * T + grp * 2 + g) * 1568 + po * 49 + yp * 7 + pp] =
            (CE * (pq2 - pq1) >= 1.0) ? 1 : 0;
      }
    }
    __syncthreads();  // B2: part free for next group's conv
  }
}

// dense1 weight limbs: 5 signed base-256 digits of round(wf1*2^39), packed as
// MFMA B-fragments with logical k = kh*16 + e.  (unchanged)
__global__ void k_limbs2(const float* __restrict__ wf1, signed char* __restrict__ BP) {
  int i = blockIdx.x * 256 + threadIdx.x;
  if (i >= 13 * 5 * 49 * 64) return;
  int lane = i & 63;
  int fi = i >> 6;
  int c = fi % 49;
  int j = (fi / 49) % 5;
  int ot = fi / 245;
  int o = ot * 32 + (lane & 31);
  int kb = 32 * c + (lane >> 5) * 16;
  int wd[4] = {0, 0, 0, 0};
#pragma unroll
  for (int e = 0; e < 16; e++) {
    float wv = (o < 410) ? wf1[(size_t)o * 1568 + kb + e] : 0.0f;
    long long m = llrint((double)wv * SC39);
    int d = 0;
    for (int jj = 0; jj <= j; jj++) {
      d = (int)((m + 128) & 255) - 128;
      m = (m - d) >> 8;
    }
    wd[e >> 2] |= (d & 255) << ((e & 3) * 8);
  }
  i32x4 v;
  v[0] = wd[0]; v[1] = wd[1]; v[2] = wd[2]; v[3] = wd[3];
  *(i32x4*)(BP + (size_t)i * 16) = v;
}

// Stage 5a: dense1 as exact i8-limb MFMA GEMM.  (unchanged)
__global__ __launch_bounds__(256) void k_dense1m(const unsigned char* __restrict__ s4,
                                                 const signed char* __restrict__ BP,
                                                 double* __restrict__ d5) {
  int ot = blockIdx.y;
  int w = threadIdx.x >> 6, l = threadIdx.x & 63;
  int col = l & 31, kh = l >> 5;
  int btTile = blockIdx.x * 4 + w;
  const unsigned char* arow = s4 + (size_t)(btTile * 32 + col) * 1568 + kh * 16;
  const i32x4* bpv = (const i32x4*)BP + (size_t)ot * 245 * 64 + l;
  i32x16 acc0, acc1, acc2, acc3, acc4;
#pragma unroll
  for (int r = 0; r < 16; r++) {
    acc0[r] = 0; acc1[r] = 0; acc2[r] = 0; acc3[r] = 0; acc4[r] = 0;
  }
  for (int c = 0; c < 49; c++) {
    i32x4 a = *(const i32x4*)(arow + 32 * c);
    i32x4 b0 = bpv[(0 * 49 + c) * 64];
    i32x4 b1 = bpv[(1 * 49 + c) * 64];
    i32x4 b2 = bpv[(2 * 49 + c) * 64];
    i32x4 b3 = bpv[(3 * 49 + c) * 64];
    i32x4 b4 = bpv[(4 * 49 + c) * 64];
    acc0 = __builtin_amdgcn_mfma_i32_32x32x32_i8(a, b0, acc0, 0, 0, 0);
    acc1 = __builtin_amdgcn_mfma_i32_32x32x32_i8(a, b1, acc1, 0, 0, 0);
    acc2 = __builtin_amdgcn_mfma_i32_32x32x32_i8(a, b2, acc2, 0, 0, 0);
    acc3 = __builtin_amdgcn_mfma_i32_32x32x32_i8(a, b3, acc3, 0, 0, 0);
    acc4 = __builtin_amdgcn_mfma_i32_32x32x32_i8(a, b4, acc4, 0, 0, 0);
  }
  int o = ot * 32 + col;
  if (o < 410) {
#pragma unroll
    for (int r = 0; r < 16; r++) {
      int R = (r & 3) + 8 * (r >> 2) + 4 * kh;
      double v = ((((double)acc4[r] * 256.0 + (double)acc3[r]) * 256.0 +
                   (double)acc2[r]) * 256.0 + (double)acc1[r]) * 256.0 + (double)acc0[r];
      d5[(size_t)(btTile * 32 + R) * 410 + o] = v * INV39;
    }
  }
}

// Stage 5b: psp + spike over dense1 output.  One thread per (b,o).
__global__ void k_psp5(const double* __restrict__ d5, unsigned char* __restrict__ s5) {
  int tid = blockIdx.x * 256 + threadIdx.x;
  if (tid >= B * 410) return;
  int o = tid % 410, b = tid / 410;
  double g1 = 0.0, g2 = 0.0;
  for (int t = 0; t < T; t++) {
    double s = d5[(size_t)(b * T + t) * 410 + o];
    g1 = s + A1 * g1;
    g2 = g1 + A1 * g2;
    s5[(size_t)(b * T + t) * 410 + o] = (CE * (g2 - g1) >= 1.0) ? 1 : 0;
  }
}

// Stage 6a: dense2 matmul.  One thread per (bt,o).
__global__ void k_dense2(const unsigned char* __restrict__ s5, const float* __restrict__ wf2,
                         double* __restrict__ d6) {
  int tid = blockIdx.x * 256 + threadIdx.x;
  if (tid >= B * T * 10) return;
  int o = tid % 10, bt = tid / 10;
  const unsigned char* sr = s5 + (size_t)bt * 410;
  const float* wr = wf2 + o * 410;
  double s = 0.0;
  for (int i = 0; i < 410; i++) s += (double)wr[i] * (double)sr[i];
  d6[tid] = s;
}

// Stage 6b: final psp + spike -> d_out [b][o][t] f32.
__global__ void k_psp6(const double* __restrict__ d6, float* __restrict__ out) {
  int tid = blockIdx.x * 256 + threadIdx.x;
  if (tid >= B * 10) return;
  int o = tid % 10, b = tid / 10;
  double g1 = 0.0, g2 = 0.0;
  for (int t = 0; t < T; t++) {
    double s = d6[(size_t)(b * T + t) * 10 + o];
    g1 = s + A1 * g1;
    g2 = g1 + A1 * g2;
    out[(size_t)b * 1000 + o * 100 + t] = (CE * (g2 - g1) >= 1.0) ? 1.0f : 0.0f;
  }
}

extern "C" void kernel_launch(void* const* d_in, const int* in_sizes, int n_in,
                              void* d_out, int out_size, void* d_ws, size_t ws_size,
                              hipStream_t stream) {
  const float* img = (const float*)d_in[0];
  const float* ru = (const float*)d_in[1];
  const float* w1 = (const float*)d_in[2];
  const float* w2 = (const float*)d_in[3];
  const float* wf1 = (const float*)d_in[4];
  const float* wf2 = (const float*)d_in[5];

  unsigned char* ws = (unsigned char*)d_ws;
  unsigned int* m1 = (unsigned int*)(ws + OFF_M1);
  unsigned int* m2 = (unsigned int*)(ws + OFF_M2);
  unsigned char* s4 = ws + OFF_S4;
  double* d5 = (double*)(ws + OFF_D5);
  unsigned char* s5 = ws + OFF_S5;
  double* d6 = (double*)(ws + OFF_D6);
  signed char* AP = (signed char*)(ws + OFF_AP);  // aliases d5 (freed before dense1m)
  signed char* BP = (signed char*)(ws + OFF_BP);
  float* out = (float*)d_out;

  k_encode_pack<<<(B * 28 * T + 255) / 256, 256, 0, stream>>>(img, ru, m1);
  k_limbs<<<(32 * 80 * 8 + 255) / 256, 256, 0, stream>>>(w2, AP);
  k_limbs2<<<(13 * 5 * 49 * 64 + 255) / 256, 256, 0, stream>>>(wf1, BP);
  k_conv1<<<B * 16, 256, 0, stream>>>(m1, w1, m2);
  k_conv2w<<<B * 7, 512, 0, stream>>>(m2, AP, s4);
  k_dense1m<<<dim3(25, 13), 256, 0, stream>>>(s4, BP, d5);
  k_psp5<<<(B * 410 + 255) / 256, 256, 0, stream>>>(d5, s5);
  k_dense2<<<(B * T * 10 + 255) / 256, 256, 0, stream>>>(s5, wf2, d6);
  k_psp6<<<2, 256, 0, stream>>>(d6, out);
}

// Round 11
// 353.484 us; speedup vs baseline: 1.9383x; 1.0636x over previous
//
#include <hip/hip_runtime.h>

// ---------------------------------------------------------------------------
// SLAYER-style spiking CNN forward pass, MI355X.  Round 9.
//
// psp (SRM alpha kernel) as double-exponential IIR cascade (exact):
//   g1[t] = x[t] + a*g1[t-1]; g2[t] = g1[t] + a*g2[t-1]; u = (e/tau)*(g2-g1)
//
// R9: k_conv1w rewrite (conv1 est. ~100-150 us, largest non-conv2 kernel;
//   "rest" stable at ~263 us across R5/R7/R8 while conv2 shrank):
//   (1) paired-pixel LUT: lut2[dy][64][2] f64, 6-bit window key; one
//       ds_read_b128 serves two adjacent pixels -> 10 gathers/thread (was
//       20), same bytes, half the LDS instructions.  Entries built with the
//       same dx-ascending f64 order -> identical values, bit-exact.
//   (2) pool-aligned mapping: thread (py,px) owns its 2x2 pixel window ->
//       conv + 4 IIR chains + pool + pool-IIR in one thread; spk/spkP LDS
//       buffers eliminated.
//   (3) __ballot m2-row assembly: tid=py*16+px -> 4 rows/wave; row mask is
//       a 16-bit ballot slice; px==0 lane stores.  ONE barrier per t (was 2).
//   conv2w (R8: 112 us, 2 waves/SIMD) and all other kernels unchanged.
// ---------------------------------------------------------------------------

namespace {
constexpr int B = 32, T = 100;
constexpr double A1 = 0.90483741803595957;  // exp(-1/10)
constexpr double CE = 0.27182818284590452;  // e/10
constexpr double SC39 = 549755813888.0;     // 2^39
constexpr double INV39 = 1.0 / 549755813888.0;

// workspace byte offsets
constexpr size_t OFF_M1 = 0;                                  // u32 [B*T][28]
constexpr size_t OFF_M2 = OFF_M1 + (size_t)B * T * 28 * 4;    // u32 [B*T][16][14]
constexpr size_t OFF_S4 = OFF_M2 + (size_t)B * T * 224 * 4;   // u8  [B*T][1568]
constexpr size_t OFF_D5 = OFF_S4 + (size_t)B * T * 1568;      // f64 [B*T][410]
constexpr size_t OFF_S5 = OFF_D5 + (size_t)B * T * 410 * 8;   // u8  [B*T][410]
constexpr size_t OFF_D6 = OFF_S5 + (size_t)B * T * 410;       // f64 [B*T][10]
constexpr size_t OFF_BP = OFF_D6 + (size_t)B * T * 10 * 8;    // i8  [13][5][49][64][16]
// A_pack (conv2 limbs) aliases the d5 region: written by k_limbs, read by
// k_conv2w, both complete before k_dense1m writes d5 (stream-ordered).
constexpr size_t OFF_AP = OFF_D5;
}  // namespace

using i32x4 = __attribute__((ext_vector_type(4))) int;
using i32x16 = __attribute__((ext_vector_type(16))) int;

// Stage 0: rate encode + bit-pack rows.  Thread per (b,y,t); loops x.
__global__ void k_encode_pack(const float* __restrict__ img, const float* __restrict__ ru,
                              unsigned int* __restrict__ m1) {
  int i = blockIdx.x * 256 + threadIdx.x;
  if (i >= B * 28 * T) return;
  int t = i % T;
  int y = (i / T) % 28;
  int b = i / (T * 28);
  unsigned int m = 0;
  const float* rb = ru + ((size_t)b * 784 + y * 28) * T + t;
  const float* ib = img + b * 784 + y * 28;
  for (int x = 0; x < 28; x++) {
    m |= (rb[(size_t)x * T] < ib[x]) ? (1u << x) : 0u;
  }
  m1[((size_t)b * T + t) * 28 + y] = m;
}

// Stage 1 fused: conv1 (1->16,5x5,pad2) + psp + spike + pool2 + psp + spike.
// Thread (py,px) owns 2x2 window; paired-pixel 16B LUT gathers; ballot row
// assembly; single barrier per t.
__global__ __launch_bounds__(256) void k_conv1w(const unsigned int* __restrict__ m1,
                                                const float* __restrict__ w1,
                                                unsigned int* __restrict__ m2) {
  __shared__ double lut2[320 * 2];       // [dy*64+f][j]; 5120 B
  __shared__ unsigned int mrow[2][32];   // rows iy=-2..29 at idx iy+2; guards 0
  int o = blockIdx.x % 16, b = blockIdx.x / 16;
  int tid = threadIdx.x;
  // build paired LUT: entry (dy,f): j=0 -> bits 0..4 of f, j=1 -> bits 1..5
  for (int e = tid; e < 320; e += 256) {
    int dy = e / 64, f = e % 64;
    const float* wb = w1 + o * 25 + dy * 5;
    double v0 = 0.0, v1 = 0.0;
#pragma unroll
    for (int dx = 0; dx < 5; dx++) {
      double wv = (double)wb[dx];
      if ((f >> dx) & 1) v0 += wv;
      if ((f >> (dx + 1)) & 1) v1 += wv;
    }
    lut2[e * 2 + 0] = v0;
    lut2[e * 2 + 1] = v1;
  }
  if (tid < 32) {
    mrow[0][tid] = 0;  // guards (0,1,30,31) stay 0 forever
    mrow[1][tid] = 0;
  }
  int py = tid >> 4, px = tid & 15;
  bool act = (px < 14) && (py < 14);
  int yA = 2 * py, xA = 2 * px;
  double g1[4] = {0, 0, 0, 0}, g2[4] = {0, 0, 0, 0};
  double q1 = 0.0, q2 = 0.0;
  const unsigned int* m1b = m1 + (size_t)b * T * 28;
  if (tid < 28) mrow[0][tid + 2] = m1b[tid] << 2;  // stage t=0 (pre-shifted)
  __syncthreads();
  for (int t = 0; t < T; t++) {
    int p = t & 1, np = p ^ 1;
    // issue next-t global load early; hidden under conv compute
    bool dold = (tid < 28) && (t + 1 < T);
    unsigned int ldv = 0;
    if (dold) ldv = m1b[(t + 1) * 28 + tid] << 2;
    unsigned int poolBit = 0;
    if (act) {
      double sAa = 0, sAb = 0, sBa = 0, sBb = 0;
      const unsigned int* mc = mrow[p];
#pragma unroll
      for (int dy = 0; dy < 5; dy++) {
        unsigned int mA = mc[yA + dy];       // pixel-row yA window row
        unsigned int mB = mc[yA + 1 + dy];   // pixel-row yA+1
        const double* eA = lut2 + (dy * 64 + (int)((mA >> xA) & 63u)) * 2;
        const double* eB = lut2 + (dy * 64 + (int)((mB >> xA) & 63u)) * 2;
        sAa += eA[0];
        sAb += eA[1];
        sBa += eB[0];
        sBb += eB[1];
      }
      g1[0] = sAa + A1 * g1[0]; g2[0] = g1[0] + A1 * g2[0];
      g1[1] = sAb + A1 * g1[1]; g2[1] = g1[1] + A1 * g2[1];
      g1[2] = sBa + A1 * g1[2]; g2[2] = g1[2] + A1 * g2[2];
      g1[3] = sBb + A1 * g1[3]; g2[3] = g1[3] + A1 * g2[3];
      int s0 = (CE * (g2[0] - g1[0]) >= 1.0) ? 1 : 0;
      int s1 = (CE * (g2[1] - g1[1]) >= 1.0) ? 1 : 0;
      int s2 = (CE * (g2[2] - g1[2]) >= 1.0) ? 1 : 0;
      int s3 = (CE * (g2[3] - g1[3]) >= 1.0) ? 1 : 0;
      double s = 1.1 * (double)(s0 + s1 + s2 + s3);
      q1 = s + A1 * q1;
      q2 = q1 + A1 * q2;
      poolBit = (CE * (q2 - q1) >= 1.0) ? 1u : 0u;
    }
    // ballot row assembly: 4 rows of 16 lanes per wave
    unsigned long long bal = __ballot((int)poolBit);
    if (act && px == 0) {
      int lane = tid & 63;
      unsigned int rm = (unsigned int)((bal >> (lane & 48)) & 0x3FFFull);
      m2[((size_t)(b * T + t) * 16 + o) * 14 + py] = rm;
    }
    if (dold) mrow[np][tid + 2] = ldv;  // late LDS-write of staged row
    __syncthreads();  // single barrier: mrow[np] staged; mrow[p] free
  }
}

// conv2 weight limbs: 5 signed base-256 digits of round(w2*2^39), laid out as
// MFMA A-fragments.  k' = (g<<3)+dx with g = 4c + 2eh + kh; row o = lane&31.
// (unchanged — layout verified bit-exact)
__global__ void k_limbs(const float* __restrict__ w2, signed char* __restrict__ AP) {
  int i = blockIdx.x * 256 + threadIdx.x;
  if (i >= 32 * 80 * 8) return;
  int dx = i & 7;
  int g = (i >> 3) % 80;
  int o = i / 640;
  int c = g >> 2, r = g & 3, eh = r >> 1, kh = r & 1;
  int lane = kh * 32 + o, e = eh * 8 + dx;
  int ci = g / 5, dy = g % 5;
  float wv = (dx < 5) ? w2[((o * 16 + ci) * 5 + dy) * 5 + dx] : 0.0f;
  long long m = llrint((double)wv * SC39);
#pragma unroll
  for (int j = 0; j < 5; j++) {
    int d = (int)((m + 128) & 255) - 128;
    AP[(size_t)((j * 20 + c) * 64 + lane) * 16 + e] = (signed char)d;
    m = (m - d) >> 8;
  }
}

// Stage 3 fused via exact i8 MFMA: conv2 + psp + spike + pool2 + psp + spike.
// Block = (b, row-pair yp), 512 threads = 8 waves = 2 timesteps x 4 K-quarters.
// 2 waves/SIMD -> MFMA of one wave overlaps VALU of the other.  (unchanged)
__global__ __launch_bounds__(512, 2) void k_conv2w(const unsigned int* __restrict__ m2,
                                                   const signed char* __restrict__ AP,
                                                   unsigned char* __restrict__ s4) {
  __shared__ unsigned int maskW[2][2][192];  // [buf][slab tp][pos]; 3072 B
  __shared__ double part[2][4][32][30];      // [tp][kq][R][col]; 61440 B
  int yp = blockIdx.x % 7, b = blockIdx.x / 7;
  int y0 = yp * 2;
  int tid = threadIdx.x;
  int w = tid >> 6, l = tid & 63;
  int tp = w & 1, kq = w >> 1;
  int col = l & 31, kh = l >> 5;
  int x = col % 14;
  unsigned int wmask = (col < 28) ? 31u : 0u;
  int half = (col >= 14) ? 1 : 0;
  const unsigned int* m2b = m2 + (size_t)b * T * 224;

  const i32x4* APv = (const i32x4*)AP;
  i32x4 Af[5][5];
#pragma unroll
  for (int j = 0; j < 5; j++)
#pragma unroll
    for (int q = 0; q < 5; q++)
      Af[j][q] = APv[(size_t)(j * 20 + 5 * kq + q) * 64 + l];

  int stPos[3] = {-1, -1, -1}, stIdx[3] = {-1, -1, -1};
  if (w < 2) {
#pragma unroll
    for (int pass = 0; pass < 3; pass++) {
      if (pass == 2 && l >= 32) continue;
      int e = pass * 64 + l;
      int H = e / 80, g = e % 80;
      int c = g >> 2, eh2 = (g >> 1) & 1, kh2 = g & 1;
      int kq2 = c / 5, q2 = c % 5;
      int ci = g / 5, dy = g % 5;
      int iy = y0 - 2 + H + dy;
      stPos[pass] = H * 96 + kh2 * 48 + kq2 * 12 + q2 * 2 + eh2;
      if (iy >= 0 && iy < 14) stIdx[pass] = ci * 14 + iy;
    }
  }

  int ct = tid - 256;
  bool chainAct = (ct >= 0) && (ct < 224);
  int po = (ct >= 0) ? ct / 7 : 0;
  int pp = (ct >= 0) ? ct % 7 : 0;
  double sg1[4] = {0, 0, 0, 0}, sg2[4] = {0, 0, 0, 0};
  double pq1 = 0.0, pq2 = 0.0;

  if (w < 2) {
#pragma unroll
    for (int pass = 0; pass < 3; pass++) {
      if (stPos[pass] < 0) continue;
      unsigned int v = 0;
      if (stIdx[pass] >= 0) v = m2b[(size_t)w * 224 + stIdx[pass]] << 2;
      maskW[0][w][stPos[pass]] = v;
    }
  }
  __syncthreads();

  for (int grp = 0; grp < 50; grp++) {
    int p = grp & 1, np = p ^ 1;

    unsigned int ld0 = 0, ld1 = 0, ld2 = 0;
    bool doStage = (w < 2) && (grp + 1 < 50);
    if (doStage) {
      size_t tb = (size_t)((grp + 1) * 2 + w) * 224;
      if (stIdx[0] >= 0) ld0 = m2b[tb + stIdx[0]] << 2;
      if (stIdx[1] >= 0) ld1 = m2b[tb + stIdx[1]] << 2;
      if (stIdx[2] >= 0) ld2 = m2b[tb + stIdx[2]] << 2;
    }

    {
      const uint4* mwv = (const uint4*)&maskW[p][tp][0];
      int base4 = half * 24 + kh * 12 + kq * 3;
      uint4 mk0 = mwv[base4 + 0], mk1 = mwv[base4 + 1], mk2 = mwv[base4 + 2];
      i32x16 ac0, ac1, ac2, ac3, ac4;
#pragma unroll
      for (int r = 0; r < 16; r++) { ac0[r] = 0; ac1[r] = 0; ac2[r] = 0; ac3[r] = 0; ac4[r] = 0; }
#pragma unroll
      for (int q = 0; q < 5; q++) {
        unsigned int ra = (q == 0) ? mk0.x : (q == 1) ? mk0.z : (q == 2) ? mk1.x
                         : (q == 3) ? mk1.z : mk2.x;
        unsigned int rb = (q == 0) ? mk0.y : (q == 1) ? mk0.w : (q == 2) ? mk1.y
                         : (q == 3) ? mk1.w : mk2.y;
        unsigned int a5 = (ra >> x) & wmask;
        unsigned int b5 = (rb >> x) & wmask;
        i32x4 bb;
        bb[0] = (int)(((a5 & 15u) * 0x204081u) & 0x01010101u);
        bb[1] = (int)((a5 >> 4) & 1u);
        bb[2] = (int)(((b5 & 15u) * 0x204081u) & 0x01010101u);
        bb[3] = (int)((b5 >> 4) & 1u);
        ac0 = __builtin_amdgcn_mfma_i32_32x32x32_i8(Af[0][q], bb, ac0, 0, 0, 0);
        ac1 = __builtin_amdgcn_mfma_i32_32x32x32_i8(Af[1][q], bb, ac1, 0, 0, 0);
        ac2 = __builtin_amdgcn_mfma_i32_32x32x32_i8(Af[2][q], bb, ac2, 0, 0, 0);
        ac3 = __builtin_amdgcn_mfma_i32_32x32x32_i8(Af[3][q], bb, ac3, 0, 0, 0);
        ac4 = __builtin_amdgcn_mfma_i32_32x32x32_i8(Af[4][q], bb, ac4, 0, 0, 0);
      }
      if (col < 28) {
#pragma unroll
        for (int r = 0; r < 16; r++) {
          int R = (r & 3) + 8 * (r >> 2) + 4 * kh;
          int c01 = ac1[r] * 256 + ac0[r];
          int c23 = ac3[r] * 256 + ac2[r];
          double S = ((double)ac4[r] * 65536.0 + (double)c23) * 65536.0 + (double)c01;
          part[tp][kq][R][col] = S;
        }
      }
    }

    if (doStage) {
      if (stPos[0] >= 0) maskW[np][w][stPos[0]] = ld0;
      if (stPos[1] >= 0) maskW[np][w][stPos[1]] = ld1;
      if (stPos[2] >= 0) maskW[np][w][stPos[2]] = ld2;
    }
    __syncthreads();  // B1: part complete + next masks staged

    if (chainAct) {
#pragma unroll
      for (int g = 0; g < 2; g++) {
        const double* q0a = &part[g][0][po][2 * pp];
        const double* q1a = &part[g][1][po][2 * pp];
        const double* q2a = &part[g][2][po][2 * pp];
        const double* q3a = &part[g][3][po][2 * pp];
        const double* q0b = &part[g][0][po][14 + 2 * pp];
        const double* q1b = &part[g][1][po][14 + 2 * pp];
        const double* q2b = &part[g][2][po][14 + 2 * pp];
        const double* q3b = &part[g][3][po][14 + 2 * pp];
        double c0 = ((q0a[0] + q1a[0]) + (q2a[0] + q3a[0])) * INV39;
        double c1 = ((q0a[1] + q1a[1]) + (q2a[1] + q3a[1])) * INV39;
        double c2 = ((q0b[0] + q1b[0]) + (q2b[0] + q3b[0])) * INV39;
        double c3 = ((q0b[1] + q1b[1]) + (q2b[1] + q3b[1])) * INV39;
        sg1[0] = c0 + A1 * sg1[0]; sg2[0] = sg1[0] + A1 * sg2[0];
        sg1[1] = c1 + A1 * sg1[1]; sg2[1] = sg1[1] + A1 * sg2[1];
        sg1[2] = c2 + A1 * sg1[2]; sg2[2] = sg1[2] + A1 * sg2[2];
        sg1[3] = c3 + A1 * sg1[3]; sg2[3] = sg1[3] + A1 * sg2[3];
        int sum = ((CE * (sg2[0] - sg1[0]) >= 1.0) ? 1 : 0)
                + ((CE * (sg2[1] - sg1[1]) >= 1.0) ? 1 : 0)
                + ((CE * (sg2[2] - sg1[2]) >= 1.0) ? 1 : 0)
                + ((CE * (sg2[3] - sg1[3]) >= 1.0) ? 1 : 0);
        double s = 1.1 * (double)sum;
        pq1 = s + A1 * pq1;
        pq2 = pq1 + A1 * pq2;
        s4[(size_t)(b * T + grp * 2 + g) * 1568 + po * 49 + yp * 7 + pp] =
            (CE * (pq2 - pq1) >= 1.0) ? 1 : 0;
      }
    }
    __syncthreads();  // B2: part free for next group's conv
  }
}

// dense1 weight limbs: 5 signed base-256 digits of round(wf1*2^39), packed as
// MFMA B-fragments with logical k = kh*16 + e.  (unchanged)
__global__ void k_limbs2(const float* __restrict__ wf1, signed char* __restrict__ BP) {
  int i = blockIdx.x * 256 + threadIdx.x;
  if (i >= 13 * 5 * 49 * 64) return;
  int lane = i & 63;
  int fi = i >> 6;
  int c = fi % 49;
  int j = (fi / 49) % 5;
  int ot = fi / 245;
  int o = ot * 32 + (lane & 31);
  int kb = 32 * c + (lane >> 5) * 16;
  int wd[4] = {0, 0, 0, 0};
#pragma unroll
  for (int e = 0; e < 16; e++) {
    float wv = (o < 410) ? wf1[(size_t)o * 1568 + kb + e] : 0.0f;
    long long m = llrint((double)wv * SC39);
    int d = 0;
    for (int jj = 0; jj <= j; jj++) {
      d = (int)((m + 128) & 255) - 128;
      m = (m - d) >> 8;
    }
    wd[e >> 2] |= (d & 255) << ((e & 3) * 8);
  }
  i32x4 v;
  v[0] = wd[0]; v[1] = wd[1]; v[2] = wd[2]; v[3] = wd[3];
  *(i32x4*)(BP + (size_t)i * 16) = v;
}

// Stage 5a: dense1 as exact i8-limb MFMA GEMM.  (unchanged)
__global__ __launch_bounds__(256) void k_dense1m(const unsigned char* __restrict__ s4,
                                                 const signed char* __restrict__ BP,
                                                 double* __restrict__ d5) {
  int ot = blockIdx.y;
  int w = threadIdx.x >> 6, l = threadIdx.x & 63;
  int col = l & 31, kh = l >> 5;
  int btTile = blockIdx.x * 4 + w;
  const unsigned char* arow = s4 + (size_t)(btTile * 32 + col) * 1568 + kh * 16;
  const i32x4* bpv = (const i32x4*)BP + (size_t)ot * 245 * 64 + l;
  i32x16 acc0, acc1, acc2, acc3, acc4;
#pragma unroll
  for (int r = 0; r < 16; r++) {
    acc0[r] = 0; acc1[r] = 0; acc2[r] = 0; acc3[r] = 0; acc4[r] = 0;
  }
  for (int c = 0; c < 49; c++) {
    i32x4 a = *(const i32x4*)(arow + 32 * c);
    i32x4 b0 = bpv[(0 * 49 + c) * 64];
    i32x4 b1 = bpv[(1 * 49 + c) * 64];
    i32x4 b2 = bpv[(2 * 49 + c) * 64];
    i32x4 b3 = bpv[(3 * 49 + c) * 64];
    i32x4 b4 = bpv[(4 * 49 + c) * 64];
    acc0 = __builtin_amdgcn_mfma_i32_32x32x32_i8(a, b0, acc0, 0, 0, 0);
    acc1 = __builtin_amdgcn_mfma_i32_32x32x32_i8(a, b1, acc1, 0, 0, 0);
    acc2 = __builtin_amdgcn_mfma_i32_32x32x32_i8(a, b2, acc2, 0, 0, 0);
    acc3 = __builtin_amdgcn_mfma_i32_32x32x32_i8(a, b3, acc3, 0, 0, 0);
    acc4 = __builtin_amdgcn_mfma_i32_32x32x32_i8(a, b4, acc4, 0, 0, 0);
  }
  int o = ot * 32 + col;
  if (o < 410) {
#pragma unroll
    for (int r = 0; r < 16; r++) {
      int R = (r & 3) + 8 * (r >> 2) + 4 * kh;
      double v = ((((double)acc4[r] * 256.0 + (double)acc3[r]) * 256.0 +
                   (double)acc2[r]) * 256.0 + (double)acc1[r]) * 256.0 + (double)acc0[r];
      d5[(size_t)(btTile * 32 + R) * 410 + o] = v * INV39;
    }
  }
}

// Stage 5b: psp + spike over dense1 output.  One thread per (b,o).
__global__ void k_psp5(const double* __restrict__ d5, unsigned char* __restrict__ s5) {
  int tid = blockIdx.x * 256 + threadIdx.x;
  if (tid >= B * 410) return;
  int o = tid % 410, b = tid / 410;
  double g1 = 0.0, g2 = 0.0;
  for (int t = 0; t < T; t++) {
    double s = d5[(size_t)(b * T + t) * 410 + o];
    g1 = s + A1 * g1;
    g2 = g1 + A1 * g2;
    s5[(size_t)(b * T + t) * 410 + o] = (CE * (g2 - g1) >= 1.0) ? 1 : 0;
  }
}

// Stage 6a: dense2 matmul.  One thread per (bt,o).
__global__ void k_dense2(const unsigned char* __restrict__ s5, const float* __restrict__ wf2,
                         double* __restrict__ d6) {
  int tid = blockIdx.x * 256 + threadIdx.x;
  if (tid >= B * T * 10) return;
  int o = tid % 10, bt = tid / 10;
  const unsigned char* sr = s5 + (size_t)bt * 410;
  const float* wr = wf2 + o * 410;
  double s = 0.0;
  for (int i = 0; i < 410; i++) s += (double)wr[i] * (double)sr[i];
  d6[tid] = s;
}

// Stage 6b: final psp + spike -> d_out [b][o][t] f32.
__global__ void k_psp6(const double* __restrict__ d6, float* __restrict__ out) {
  int tid = blockIdx.x * 256 + threadIdx.x;
  if (tid >= B * 10) return;
  int o = tid % 10, b = tid / 10;
  double g1 = 0.0, g2 = 0.0;
  for (int t = 0; t < T; t++) {
    double s = d6[(size_t)(b * T + t) * 10 + o];
    g1 = s + A1 * g1;
    g2 = g1 + A1 * g2;
    out[(size_t)b * 1000 + o * 100 + t] = (CE * (g2 - g1) >= 1.0) ? 1.0f : 0.0f;
  }
}

extern "C" void kernel_launch(void* const* d_in, const int* in_sizes, int n_in,
                              void* d_out, int out_size, void* d_ws, size_t ws_size,
                              hipStream_t stream) {
  const float* img = (const float*)d_in[0];
  const float* ru = (const float*)d_in[1];
  const float* w1 = (const float*)d_in[2];
  const float* w2 = (const float*)d_in[3];
  const float* wf1 = (const float*)d_in[4];
  const float* wf2 = (const float*)d_in[5];

  unsigned char* ws = (unsigned char*)d_ws;
  unsigned int* m1 = (unsigned int*)(ws + OFF_M1);
  unsigned int* m2 = (unsigned int*)(ws + OFF_M2);
  unsigned char* s4 = ws + OFF_S4;
  double* d5 = (double*)(ws + OFF_D5);
  unsigned char* s5 = ws + OFF_S5;
  double* d6 = (double*)(ws + OFF_D6);
  signed char* AP = (signed char*)(ws + OFF_AP);  // aliases d5 (freed before dense1m)
  signed char* BP = (signed char*)(ws + OFF_BP);
  float* out = (float*)d_out;

  k_encode_pack<<<(B * 28 * T + 255) / 256, 256, 0, stream>>>(img, ru, m1);
  k_limbs<<<(32 * 80 * 8 + 255) / 256, 256, 0, stream>>>(w2, AP);
  k_limbs2<<<(13 * 5 * 49 * 64 + 255) / 256, 256, 0, stream>>>(wf1, BP);
  k_conv1w<<<B * 16, 256, 0, stream>>>(m1, w1, m2);
  k_conv2w<<<B * 7, 512, 0, stream>>>(m2, AP, s4);
  k_dense1m<<<dim3(25, 13), 256, 0, stream>>>(s4, BP, d5);
  k_psp5<<<(B * 410 + 255) / 256, 256, 0, stream>>>(d5, s5);
  k_dense2<<<(B * T * 10 + 255) / 256, 256, 0, stream>>>(s5, wf2, d6);
  k_psp6<<<2, 256, 0, stream>>>(d6, out);
}

// Round 12
// 345.476 us; speedup vs baseline: 1.9833x; 1.0232x over previous
//
#include <hip/hip_runtime.h>

// ---------------------------------------------------------------------------
// SLAYER-style spiking CNN forward pass, MI355X.  Round 10.
//
// psp (SRM alpha kernel) as double-exponential IIR cascade (exact):
//   g1[t] = x[t] + a*g1[t-1]; g2[t] = g1[t] + a*g2[t-1]; u = (e/tau)*(g2-g1)
//
// R10: k_conv2v = conv2w with the cross-kq reduction moved to exact integer
//   LDS atomics.  R9 measured 5600 cyc/group vs ~3000 modeled; the gap is
//   the part[] exchange: 61 KB staging, 16-gather IIR fan-in, and barrier
//   B2 putting the IIR phase on every group's critical path.
//   Per-wave partials are exact integers < 2^47 -> atomicAdd(u64) into
//   part[parity][tp][32][30] (30 KB, double-buffered):
//   - B2 eliminated (1 barrier/group): IIR-g reads+ZEROS part[p] while
//     conv-(g+1) atomically adds part[np] — disjoint ownership.
//   - IIR fan-in 16 gathers -> 4 u64 reads; kq-sum adds gone.
//   - recombine in i64 (shift/add) instead of f64 Horner.
//   Bit-exact: same integer total -> exact i64->f64 cvt -> same *INV39.
//   All other kernels unchanged from R9.
// ---------------------------------------------------------------------------

namespace {
constexpr int B = 32, T = 100;
constexpr double A1 = 0.90483741803595957;  // exp(-1/10)
constexpr double CE = 0.27182818284590452;  // e/10
constexpr double SC39 = 549755813888.0;     // 2^39
constexpr double INV39 = 1.0 / 549755813888.0;

// workspace byte offsets
constexpr size_t OFF_M1 = 0;                                  // u32 [B*T][28]
constexpr size_t OFF_M2 = OFF_M1 + (size_t)B * T * 28 * 4;    // u32 [B*T][16][14]
constexpr size_t OFF_S4 = OFF_M2 + (size_t)B * T * 224 * 4;   // u8  [B*T][1568]
constexpr size_t OFF_D5 = OFF_S4 + (size_t)B * T * 1568;      // f64 [B*T][410]
constexpr size_t OFF_S5 = OFF_D5 + (size_t)B * T * 410 * 8;   // u8  [B*T][410]
constexpr size_t OFF_D6 = OFF_S5 + (size_t)B * T * 410;       // f64 [B*T][10]
constexpr size_t OFF_BP = OFF_D6 + (size_t)B * T * 10 * 8;    // i8  [13][5][49][64][16]
// A_pack (conv2 limbs) aliases the d5 region: written by k_limbs, read by
// k_conv2v, both complete before k_dense1m writes d5 (stream-ordered).
constexpr size_t OFF_AP = OFF_D5;
}  // namespace

using i32x4 = __attribute__((ext_vector_type(4))) int;
using i32x16 = __attribute__((ext_vector_type(16))) int;

// Stage 0: rate encode + bit-pack rows.  Thread per (b,y,t); loops x.
__global__ void k_encode_pack(const float* __restrict__ img, const float* __restrict__ ru,
                              unsigned int* __restrict__ m1) {
  int i = blockIdx.x * 256 + threadIdx.x;
  if (i >= B * 28 * T) return;
  int t = i % T;
  int y = (i / T) % 28;
  int b = i / (T * 28);
  unsigned int m = 0;
  const float* rb = ru + ((size_t)b * 784 + y * 28) * T + t;
  const float* ib = img + b * 784 + y * 28;
  for (int x = 0; x < 28; x++) {
    m |= (rb[(size_t)x * T] < ib[x]) ? (1u << x) : 0u;
  }
  m1[((size_t)b * T + t) * 28 + y] = m;
}

// Stage 1 fused: conv1 (1->16,5x5,pad2) + psp + spike + pool2 + psp + spike.
// (unchanged from R9: paired-pixel LUT, pool-aligned mapping, ballot rows)
__global__ __launch_bounds__(256) void k_conv1w(const unsigned int* __restrict__ m1,
                                                const float* __restrict__ w1,
                                                unsigned int* __restrict__ m2) {
  __shared__ double lut2[320 * 2];       // [dy*64+f][j]; 5120 B
  __shared__ unsigned int mrow[2][32];   // rows iy=-2..29 at idx iy+2; guards 0
  int o = blockIdx.x % 16, b = blockIdx.x / 16;
  int tid = threadIdx.x;
  for (int e = tid; e < 320; e += 256) {
    int dy = e / 64, f = e % 64;
    const float* wb = w1 + o * 25 + dy * 5;
    double v0 = 0.0, v1 = 0.0;
#pragma unroll
    for (int dx = 0; dx < 5; dx++) {
      double wv = (double)wb[dx];
      if ((f >> dx) & 1) v0 += wv;
      if ((f >> (dx + 1)) & 1) v1 += wv;
    }
    lut2[e * 2 + 0] = v0;
    lut2[e * 2 + 1] = v1;
  }
  if (tid < 32) {
    mrow[0][tid] = 0;
    mrow[1][tid] = 0;
  }
  int py = tid >> 4, px = tid & 15;
  bool act = (px < 14) && (py < 14);
  int yA = 2 * py, xA = 2 * px;
  double g1[4] = {0, 0, 0, 0}, g2[4] = {0, 0, 0, 0};
  double q1 = 0.0, q2 = 0.0;
  const unsigned int* m1b = m1 + (size_t)b * T * 28;
  if (tid < 28) mrow[0][tid + 2] = m1b[tid] << 2;
  __syncthreads();
  for (int t = 0; t < T; t++) {
    int p = t & 1, np = p ^ 1;
    bool dold = (tid < 28) && (t + 1 < T);
    unsigned int ldv = 0;
    if (dold) ldv = m1b[(t + 1) * 28 + tid] << 2;
    unsigned int poolBit = 0;
    if (act) {
      double sAa = 0, sAb = 0, sBa = 0, sBb = 0;
      const unsigned int* mc = mrow[p];
#pragma unroll
      for (int dy = 0; dy < 5; dy++) {
        unsigned int mA = mc[yA + dy];
        unsigned int mB = mc[yA + 1 + dy];
        const double* eA = lut2 + (dy * 64 + (int)((mA >> xA) & 63u)) * 2;
        const double* eB = lut2 + (dy * 64 + (int)((mB >> xA) & 63u)) * 2;
        sAa += eA[0];
        sAb += eA[1];
        sBa += eB[0];
        sBb += eB[1];
      }
      g1[0] = sAa + A1 * g1[0]; g2[0] = g1[0] + A1 * g2[0];
      g1[1] = sAb + A1 * g1[1]; g2[1] = g1[1] + A1 * g2[1];
      g1[2] = sBa + A1 * g1[2]; g2[2] = g1[2] + A1 * g2[2];
      g1[3] = sBb + A1 * g1[3]; g2[3] = g1[3] + A1 * g2[3];
      int s0 = (CE * (g2[0] - g1[0]) >= 1.0) ? 1 : 0;
      int s1 = (CE * (g2[1] - g1[1]) >= 1.0) ? 1 : 0;
      int s2 = (CE * (g2[2] - g1[2]) >= 1.0) ? 1 : 0;
      int s3 = (CE * (g2[3] - g1[3]) >= 1.0) ? 1 : 0;
      double s = 1.1 * (double)(s0 + s1 + s2 + s3);
      q1 = s + A1 * q1;
      q2 = q1 + A1 * q2;
      poolBit = (CE * (q2 - q1) >= 1.0) ? 1u : 0u;
    }
    unsigned long long bal = __ballot((int)poolBit);
    if (act && px == 0) {
      int lane = tid & 63;
      unsigned int rm = (unsigned int)((bal >> (lane & 48)) & 0x3FFFull);
      m2[((size_t)(b * T + t) * 16 + o) * 14 + py] = rm;
    }
    if (dold) mrow[np][tid + 2] = ldv;
    __syncthreads();
  }
}

// conv2 weight limbs: 5 signed base-256 digits of round(w2*2^39), laid out as
// MFMA A-fragments.  (unchanged — layout verified bit-exact)
__global__ void k_limbs(const float* __restrict__ w2, signed char* __restrict__ AP) {
  int i = blockIdx.x * 256 + threadIdx.x;
  if (i >= 32 * 80 * 8) return;
  int dx = i & 7;
  int g = (i >> 3) % 80;
  int o = i / 640;
  int c = g >> 2, r = g & 3, eh = r >> 1, kh = r & 1;
  int lane = kh * 32 + o, e = eh * 8 + dx;
  int ci = g / 5, dy = g % 5;
  float wv = (dx < 5) ? w2[((o * 16 + ci) * 5 + dy) * 5 + dx] : 0.0f;
  long long m = llrint((double)wv * SC39);
#pragma unroll
  for (int j = 0; j < 5; j++) {
    int d = (int)((m + 128) & 255) - 128;
    AP[(size_t)((j * 20 + c) * 64 + lane) * 16 + e] = (signed char)d;
    m = (m - d) >> 8;
  }
}

// Stage 3 fused via exact i8 MFMA: conv2 + psp + spike + pool2 + psp + spike.
// Block = (b, row-pair yp), 512 threads = 8 waves = 2 timesteps x 4 K-quarters.
// Cross-kq reduction via LDS atomicAdd(u64) on exact integer partials;
// part double-buffered by parity -> ONE barrier per group.
__global__ __launch_bounds__(512, 2) void k_conv2v(const unsigned int* __restrict__ m2,
                                                   const signed char* __restrict__ AP,
                                                   unsigned char* __restrict__ s4) {
  __shared__ unsigned int maskW[2][2][192];          // [buf][slab tp][pos]; 3072 B
  __shared__ unsigned long long part[2][2][32][30];  // [parity][tp][R][col]; 30720 B
  int yp = blockIdx.x % 7, b = blockIdx.x / 7;
  int y0 = yp * 2;
  int tid = threadIdx.x;
  int w = tid >> 6, l = tid & 63;
  int tp = w & 1, kq = w >> 1;
  int col = l & 31, kh = l >> 5;
  int x = col % 14;
  unsigned int wmask = (col < 28) ? 31u : 0u;
  int half = (col >= 14) ? 1 : 0;
  const unsigned int* m2b = m2 + (size_t)b * T * 224;

  // ---- A preload: 5 limbs x 5 chunks (global chunk 5kq+q) = 25 frags ----
  const i32x4* APv = (const i32x4*)AP;
  i32x4 Af[5][5];
#pragma unroll
  for (int j = 0; j < 5; j++)
#pragma unroll
    for (int q = 0; q < 5; q++)
      Af[j][q] = APv[(size_t)(j * 20 + 5 * kq + q) * 64 + l];

  // ---- stager constants (waves 0,1 = slabs tp 0,1) ----
  int stPos[3] = {-1, -1, -1}, stIdx[3] = {-1, -1, -1};
  if (w < 2) {
#pragma unroll
    for (int pass = 0; pass < 3; pass++) {
      if (pass == 2 && l >= 32) continue;
      int e = pass * 64 + l;
      int H = e / 80, g = e % 80;
      int c = g >> 2, eh2 = (g >> 1) & 1, kh2 = g & 1;
      int kq2 = c / 5, q2 = c % 5;
      int ci = g / 5, dy = g % 5;
      int iy = y0 - 2 + H + dy;
      stPos[pass] = H * 96 + kh2 * 48 + kq2 * 12 + q2 * 2 + eh2;
      if (iy >= 0 && iy < 14) stIdx[pass] = ci * 14 + iy;
    }
  }

  // ---- chain mapping: waves 4-7 -> ct in [0,224): (po, pp) ----
  int ct = tid - 256;
  bool chainAct = (ct >= 0) && (ct < 224);
  int po = (ct >= 0) ? ct / 7 : 0;
  int pp = (ct >= 0) ? ct % 7 : 0;
  double sg1[4] = {0, 0, 0, 0}, sg2[4] = {0, 0, 0, 0};  // spike IIR per col
  double pq1 = 0.0, pq2 = 0.0;                          // pool IIR

  // ---- prologue: zero part (both parities); stage masks for t=0,1 ----
  {
    unsigned long long* pf = &part[0][0][0][0];
    for (int e = tid; e < 2 * 2 * 32 * 30; e += 512) pf[e] = 0ull;
  }
  if (w < 2) {
#pragma unroll
    for (int pass = 0; pass < 3; pass++) {
      if (stPos[pass] < 0) continue;
      unsigned int v = 0;
      if (stIdx[pass] >= 0) v = m2b[(size_t)w * 224 + stIdx[pass]] << 2;
      maskW[0][w][stPos[pass]] = v;
    }
  }
  __syncthreads();

  for (int grp = 0; grp < 50; grp++) {
    int p = grp & 1, np = p ^ 1;

    // issue next-group mask loads early (hidden under conv)
    unsigned int ld0 = 0, ld1 = 0, ld2 = 0;
    bool doStage = (w < 2) && (grp + 1 < 50);
    if (doStage) {
      size_t tb = (size_t)((grp + 1) * 2 + w) * 224;
      if (stIdx[0] >= 0) ld0 = m2b[tb + stIdx[0]] << 2;
      if (stIdx[1] >= 0) ld1 = m2b[tb + stIdx[1]] << 2;
      if (stIdx[2] >= 0) ld2 = m2b[tb + stIdx[2]] << 2;
    }

    // conv: this wave's (t = grp*2+tp, K-quarter kq), all 5 limbs
    {
      const uint4* mwv = (const uint4*)&maskW[p][tp][0];
      int base4 = half * 24 + kh * 12 + kq * 3;
      uint4 mk0 = mwv[base4 + 0], mk1 = mwv[base4 + 1], mk2 = mwv[base4 + 2];
      i32x16 ac0, ac1, ac2, ac3, ac4;
#pragma unroll
      for (int r = 0; r < 16; r++) { ac0[r] = 0; ac1[r] = 0; ac2[r] = 0; ac3[r] = 0; ac4[r] = 0; }
#pragma unroll
      for (int q = 0; q < 5; q++) {
        unsigned int ra = (q == 0) ? mk0.x : (q == 1) ? mk0.z : (q == 2) ? mk1.x
                         : (q == 3) ? mk1.z : mk2.x;
        unsigned int rb = (q == 0) ? mk0.y : (q == 1) ? mk0.w : (q == 2) ? mk1.y
                         : (q == 3) ? mk1.w : mk2.y;
        unsigned int a5 = (ra >> x) & wmask;
        unsigned int b5 = (rb >> x) & wmask;
        i32x4 bb;
        bb[0] = (int)(((a5 & 15u) * 0x204081u) & 0x01010101u);
        bb[1] = (int)((a5 >> 4) & 1u);
        bb[2] = (int)(((b5 & 15u) * 0x204081u) & 0x01010101u);
        bb[3] = (int)((b5 >> 4) & 1u);
        ac0 = __builtin_amdgcn_mfma_i32_32x32x32_i8(Af[0][q], bb, ac0, 0, 0, 0);
        ac1 = __builtin_amdgcn_mfma_i32_32x32x32_i8(Af[1][q], bb, ac1, 0, 0, 0);
        ac2 = __builtin_amdgcn_mfma_i32_32x32x32_i8(Af[2][q], bb, ac2, 0, 0, 0);
        ac3 = __builtin_amdgcn_mfma_i32_32x32x32_i8(Af[3][q], bb, ac3, 0, 0, 0);
        ac4 = __builtin_amdgcn_mfma_i32_32x32x32_i8(Af[4][q], bb, ac4, 0, 0, 0);
      }
      // exact i64 limb recombine; atomic add into part[p] (u64 wrap = exact)
      if (col < 28) {
#pragma unroll
        for (int r = 0; r < 16; r++) {
          int R = (r & 3) + 8 * (r >> 2) + 4 * kh;
          int c01 = ac1[r] * 256 + ac0[r];
          int c23 = ac3[r] * 256 + ac2[r];
          long long S = (long long)ac4[r] * 4294967296LL +
                        (long long)c23 * 65536LL + (long long)c01;
          atomicAdd(&part[p][tp][R][col], (unsigned long long)S);
        }
      }
    }

    // late LDS-write of staged masks (loads hidden under conv)
    if (doStage) {
      if (stPos[0] >= 0) maskW[np][w][stPos[0]] = ld0;
      if (stPos[1] >= 0) maskW[np][w][stPos[1]] = ld1;
      if (stPos[2] >= 0) maskW[np][w][stPos[2]] = ld2;
    }
    __syncthreads();  // single barrier: part[p] sums complete + masks staged

    // merged IIR + pool (waves 4-7): read part[p], ZERO it for reuse.
    // Next group's conv adds into part[np] — disjoint; no second barrier.
    if (chainAct) {
#pragma unroll
      for (int g = 0; g < 2; g++) {
        unsigned long long v0 = part[p][g][po][2 * pp];
        unsigned long long v1 = part[p][g][po][2 * pp + 1];
        unsigned long long v2 = part[p][g][po][14 + 2 * pp];
        unsigned long long v3 = part[p][g][po][15 + 2 * pp];
        part[p][g][po][2 * pp] = 0ull;
        part[p][g][po][2 * pp + 1] = 0ull;
        part[p][g][po][14 + 2 * pp] = 0ull;
        part[p][g][po][15 + 2 * pp] = 0ull;
        double c0 = (double)(long long)v0 * INV39;
        double c1 = (double)(long long)v1 * INV39;
        double c2 = (double)(long long)v2 * INV39;
        double c3 = (double)(long long)v3 * INV39;
        sg1[0] = c0 + A1 * sg1[0]; sg2[0] = sg1[0] + A1 * sg2[0];
        sg1[1] = c1 + A1 * sg1[1]; sg2[1] = sg1[1] + A1 * sg2[1];
        sg1[2] = c2 + A1 * sg1[2]; sg2[2] = sg1[2] + A1 * sg2[2];
        sg1[3] = c3 + A1 * sg1[3]; sg2[3] = sg1[3] + A1 * sg2[3];
        int sum = ((CE * (sg2[0] - sg1[0]) >= 1.0) ? 1 : 0)
                + ((CE * (sg2[1] - sg1[1]) >= 1.0) ? 1 : 0)
                + ((CE * (sg2[2] - sg1[2]) >= 1.0) ? 1 : 0)
                + ((CE * (sg2[3] - sg1[3]) >= 1.0) ? 1 : 0);
        double s = 1.1 * (double)sum;
        pq1 = s + A1 * pq1;
        pq2 = pq1 + A1 * pq2;
        s4[(size_t)(b * T + grp * 2 + g) * 1568 + po * 49 + yp * 7 + pp] =
            (CE * (pq2 - pq1) >= 1.0) ? 1 : 0;
      }
    }
  }
}

// dense1 weight limbs: 5 signed base-256 digits of round(wf1*2^39), packed as
// MFMA B-fragments with logical k = kh*16 + e.  (unchanged)
__global__ void k_limbs2(const float* __restrict__ wf1, signed char* __restrict__ BP) {
  int i = blockIdx.x * 256 + threadIdx.x;
  if (i >= 13 * 5 * 49 * 64) return;
  int lane = i & 63;
  int fi = i >> 6;
  int c = fi % 49;
  int j = (fi / 49) % 5;
  int ot = fi / 245;
  int o = ot * 32 + (lane & 31);
  int kb = 32 * c + (lane >> 5) * 16;
  int wd[4] = {0, 0, 0, 0};
#pragma unroll
  for (int e = 0; e < 16; e++) {
    float wv = (o < 410) ? wf1[(size_t)o * 1568 + kb + e] : 0.0f;
    long long m = llrint((double)wv * SC39);
    int d = 0;
    for (int jj = 0; jj <= j; jj++) {
      d = (int)((m + 128) & 255) - 128;
      m = (m - d) >> 8;
    }
    wd[e >> 2] |= (d & 255) << ((e & 3) * 8);
  }
  i32x4 v;
  v[0] = wd[0]; v[1] = wd[1]; v[2] = wd[2]; v[3] = wd[3];
  *(i32x4*)(BP + (size_t)i * 16) = v;
}

// Stage 5a: dense1 as exact i8-limb MFMA GEMM.  (unchanged)
__global__ __launch_bounds__(256) void k_dense1m(const unsigned char* __restrict__ s4,
                                                 const signed char* __restrict__ BP,
                                                 double* __restrict__ d5) {
  int ot = blockIdx.y;
  int w = threadIdx.x >> 6, l = threadIdx.x & 63;
  int col = l & 31, kh = l >> 5;
  int btTile = blockIdx.x * 4 + w;
  const unsigned char* arow = s4 + (size_t)(btTile * 32 + col) * 1568 + kh * 16;
  const i32x4* bpv = (const i32x4*)BP + (size_t)ot * 245 * 64 + l;
  i32x16 acc0, acc1, acc2, acc3, acc4;
#pragma unroll
  for (int r = 0; r < 16; r++) {
    acc0[r] = 0; acc1[r] = 0; acc2[r] = 0; acc3[r] = 0; acc4[r] = 0;
  }
  for (int c = 0; c < 49; c++) {
    i32x4 a = *(const i32x4*)(arow + 32 * c);
    i32x4 b0 = bpv[(0 * 49 + c) * 64];
    i32x4 b1 = bpv[(1 * 49 + c) * 64];
    i32x4 b2 = bpv[(2 * 49 + c) * 64];
    i32x4 b3 = bpv[(3 * 49 + c) * 64];
    i32x4 b4 = bpv[(4 * 49 + c) * 64];
    acc0 = __builtin_amdgcn_mfma_i32_32x32x32_i8(a, b0, acc0, 0, 0, 0);
    acc1 = __builtin_amdgcn_mfma_i32_32x32x32_i8(a, b1, acc1, 0, 0, 0);
    acc2 = __builtin_amdgcn_mfma_i32_32x32x32_i8(a, b2, acc2, 0, 0, 0);
    acc3 = __builtin_amdgcn_mfma_i32_32x32x32_i8(a, b3, acc3, 0, 0, 0);
    acc4 = __builtin_amdgcn_mfma_i32_32x32x32_i8(a, b4, acc4, 0, 0, 0);
  }
  int o = ot * 32 + col;
  if (o < 410) {
#pragma unroll
    for (int r = 0; r < 16; r++) {
      int R = (r & 3) + 8 * (r >> 2) + 4 * kh;
      double v = ((((double)acc4[r] * 256.0 + (double)acc3[r]) * 256.0 +
                   (double)acc2[r]) * 256.0 + (double)acc1[r]) * 256.0 + (double)acc0[r];
      d5[(size_t)(btTile * 32 + R) * 410 + o] = v * INV39;
    }
  }
}

// Stage 5b: psp + spike over dense1 output.  One thread per (b,o).
__global__ void k_psp5(const double* __restrict__ d5, unsigned char* __restrict__ s5) {
  int tid = blockIdx.x * 256 + threadIdx.x;
  if (tid >= B * 410) return;
  int o = tid % 410, b = tid / 410;
  double g1 = 0.0, g2 = 0.0;
  for (int t = 0; t < T; t++) {
    double s = d5[(size_t)(b * T + t) * 410 + o];
    g1 = s + A1 * g1;
    g2 = g1 + A1 * g2;
    s5[(size_t)(b * T + t) * 410 + o] = (CE * (g2 - g1) >= 1.0) ? 1 : 0;
  }
}

// Stage 6a: dense2 matmul.  One thread per (bt,o).
__global__ void k_dense2(const unsigned char* __restrict__ s5, const float* __restrict__ wf2,
                         double* __restrict__ d6) {
  int tid = blockIdx.x * 256 + threadIdx.x;
  if (tid >= B * T * 10) return;
  int o = tid % 10, bt = tid / 10;
  const unsigned char* sr = s5 + (size_t)bt * 410;
  const float* wr = wf2 + o * 410;
  double s = 0.0;
  for (int i = 0; i < 410; i++) s += (double)wr[i] * (double)sr[i];
  d6[tid] = s;
}

// Stage 6b: final psp + spike -> d_out [b][o][t] f32.
__global__ void k_psp6(const double* __restrict__ d6, float* __restrict__ out) {
  int tid = blockIdx.x * 256 + threadIdx.x;
  if (tid >= B * 10) return;
  int o = tid % 10, b = tid / 10;
  double g1 = 0.0, g2 = 0.0;
  for (int t = 0; t < T; t++) {
    double s = d6[(size_t)(b * T + t) * 10 + o];
    g1 = s + A1 * g1;
    g2 = g1 + A1 * g2;
    out[(size_t)b * 1000 + o * 100 + t] = (CE * (g2 - g1) >= 1.0) ? 1.0f : 0.0f;
  }
}

extern "C" void kernel_launch(void* const* d_in, const int* in_sizes, int n_in,
                              void* d_out, int out_size, void* d_ws, size_t ws_size,
                              hipStream_t stream) {
  const float* img = (const float*)d_in[0];
  const float* ru = (const float*)d_in[1];
  const float* w1 = (const float*)d_in[2];
  const float* w2 = (const float*)d_in[3];
  const float* wf1 = (const float*)d_in[4];
  const float* wf2 = (const float*)d_in[5];

  unsigned char* ws = (unsigned char*)d_ws;
  unsigned int* m1 = (unsigned int*)(ws + OFF_M1);
  unsigned int* m2 = (unsigned int*)(ws + OFF_M2);
  unsigned char* s4 = ws + OFF_S4;
  double* d5 = (double*)(ws + OFF_D5);
  unsigned char* s5 = ws + OFF_S5;
  double* d6 = (double*)(ws + OFF_D6);
  signed char* AP = (signed char*)(ws + OFF_AP);  // aliases d5 (freed before dense1m)
  signed char* BP = (signed char*)(ws + OFF_BP);
  float* out = (float*)d_out;

  k_encode_pack<<<(B * 28 * T + 255) / 256, 256, 0, stream>>>(img, ru, m1);
  k_limbs<<<(32 * 80 * 8 + 255) / 256, 256, 0, stream>>>(w2, AP);
  k_limbs2<<<(13 * 5 * 49 * 64 + 255) / 256, 256, 0, stream>>>(wf1, BP);
  k_conv1w<<<B * 16, 256, 0, stream>>>(m1, w1, m2);
  k_conv2v<<<B * 7, 512, 0, stream>>>(m2, AP, s4);
  k_dense1m<<<dim3(25, 13), 256, 0, stream>>>(s4, BP, d5);
  k_psp5<<<(B * 410 + 255) / 256, 256, 0, stream>>>(d5, s5);
  k_dense2<<<(B * T * 10 + 255) / 256, 256, 0, stream>>>(s5, wf2, d6);
  k_psp6<<<2, 256, 0, stream>>>(d6, out);
}